// Round 4
// baseline (362.142 us; speedup 1.0000x reference)
//
#include <hip/hip_runtime.h>

// Problem constants (fixed by the reference)
#define N_NODES 20000
#define N_EDGES 320000
#define ETOT    (N_EDGES + N_NODES)   // edges + self-loops = 340000
#define HEADS   10
#define F_IN    32
#define C1      (HEADS * F_IN)        // 320
#define C2      128
#define NB      100
#define PER     200
#define MAXDEG  128                   // chunk size for per-node edge lists
#define PSTRIDE 11                    // sh_p stride: gcd(11,32)=1 -> conflict-free

typedef __attribute__((ext_vector_type(8))) short bf16x8;   // MFMA A/B frag (4 VGPRs)
typedef __attribute__((ext_vector_type(4))) float floatx4;  // MFMA C/D frag

static __device__ __forceinline__ unsigned short f2bf(float f) {
    unsigned int u = __float_as_uint(f);
    unsigned int r = (u + 0x7fffu + ((u >> 16) & 1u)) >> 16;   // RNE
    return (unsigned short)r;
}
static __device__ __forceinline__ float bf2f(unsigned short b) {
    return __uint_as_float(((unsigned int)b) << 16);
}

// ---------------------------------------------------------------------------
// CSR histogram + W2 MFMA-fragment prep (independent work, one launch)
// W2p[((kb*8 + ct)*64 + lane)*8 + j] = bf16(W2[(kb*32 + (lane>>4)*8 + j)*128 + ct*16 + (lane&15)])
// ---------------------------------------------------------------------------
#define HIST_BLOCKS ((ETOT + 255) / 256)
__global__ void hist_w2prep_kernel(const int* __restrict__ ei, int* __restrict__ counts,
                                   const float* __restrict__ W2, unsigned short* __restrict__ W2p) {
    if (blockIdx.x < HIST_BLOCKS) {
        int e = blockIdx.x * 256 + threadIdx.x;
        if (e >= ETOT) return;
        int d = (e < N_EDGES) ? ei[N_EDGES + e] : (e - N_EDGES);
        atomicAdd(&counts[d], 1);
    } else {
        int o = (blockIdx.x - HIST_BLOCKS) * 256 + threadIdx.x;   // 40960 total
        if (o >= C1 * C2) return;
        int j    = o & 7;
        int lane = (o >> 3) & 63;
        int ct   = (o >> 9) & 7;
        int kb   = o >> 12;
        int k = kb * 32 + (lane >> 4) * 8 + j;
        int n = ct * 16 + (lane & 15);
        W2p[o] = f2bf(W2[k * C2 + n]);
    }
}

__global__ void scan_kernel(const int* __restrict__ counts, int* __restrict__ row_start) {
    __shared__ int sums[1024];
    int tid = threadIdx.x;
    const int per = (N_NODES + 1023) / 1024;  // 20
    int base = tid * per;
    int s = 0;
    for (int i = 0; i < per; i++) {
        int idx = base + i;
        if (idx < N_NODES) s += counts[idx];
    }
    sums[tid] = s;
    __syncthreads();
    for (int off = 1; off < 1024; off <<= 1) {
        int v = (tid >= off) ? sums[tid - off] : 0;
        __syncthreads();
        sums[tid] += v;
        __syncthreads();
    }
    int run = (tid == 0) ? 0 : sums[tid - 1];
    for (int i = 0; i < per; i++) {
        int idx = base + i;
        if (idx < N_NODES) { row_start[idx] = run; run += counts[idx]; }
    }
    if (tid == 1023) row_start[N_NODES] = run;  // = ETOT
}

__global__ void scatter_kernel(const int* __restrict__ ei, const int* __restrict__ row_start,
                               int* __restrict__ cursor, int* __restrict__ csr_src) {
    int e = blockIdx.x * blockDim.x + threadIdx.x;
    if (e >= ETOT) return;
    int s, d;
    if (e < N_EDGES) { s = ei[e]; d = ei[N_EDGES + e]; }
    else             { s = e - N_EDGES; d = s; }
    int pos = atomicAdd(&cursor[d], 1);
    csr_src[row_start[d] + pos] = s;
}

// ---------------------------------------------------------------------------
// Layer 1: xw1 = feats @ W1 (stored bf16), attention scores s_src/s_dst fp32
// block: 320 threads (t = h*32+f), 8 nodes per block
// ---------------------------------------------------------------------------
__global__ void gemm1_kernel(const float* __restrict__ x, const float* __restrict__ W1,
                             const float* __restrict__ a_src, const float* __restrict__ a_dst,
                             unsigned short* __restrict__ xw1b, float* __restrict__ s_src,
                             float* __restrict__ s_dst) {
    __shared__ float w[F_IN * C1];   // 40 KB
    __shared__ float xr[8][F_IN];
    int t = threadIdx.x;
    for (int i = t; i < F_IN * C1; i += C1) w[i] = W1[i];
    int n0 = blockIdx.x * 8;
    for (int i = t; i < 8 * F_IN; i += C1) {
        int r = i >> 5, c = i & 31;
        xr[r][c] = x[(n0 + r) * F_IN + c];
    }
    __syncthreads();
    int h = t >> 5, f = t & 31;
    float as = a_src[t];
    float ad = a_dst[t];
    for (int r = 0; r < 8; r++) {
        int n = n0 + r;
        float acc = 0.f;
#pragma unroll
        for (int k = 0; k < F_IN; k++) acc += xr[r][k] * w[k * C1 + t];
        xw1b[(size_t)n * C1 + t] = f2bf(acc);
        float vs = acc * as, vd = acc * ad;
#pragma unroll
        for (int off = 16; off >= 1; off >>= 1) {
            vs += __shfl_xor(vs, off);
            vd += __shfl_xor(vd, off);
        }
        if (f == 0) { s_src[n * HEADS + h] = vs; s_dst[n * HEADS + h] = vd; }
    }
}

// ---------------------------------------------------------------------------
// Layer 1 aggregation: two-phase softmax; phase B gathers ushort4 (4 channels)
// thread t = h*32 + lane32; lane32 = sub*8 + quad
//   quad: channel quad within head (channels h*32 + 4*quad .. +3)
//   sub:  edge subgroup (edges i ≡ sub mod 4)
// subgroup partials combined via shfl_xor(8,16); 80 lanes store ushort4.
// ---------------------------------------------------------------------------
__global__ __launch_bounds__(320) void agg1_kernel(
        const unsigned short* __restrict__ xw1b, const float* __restrict__ s_src,
        const float* __restrict__ s_dst, const int* __restrict__ row_start,
        const int* __restrict__ csr_src, const float* __restrict__ b1,
        unsigned short* __restrict__ h1b) {
    __shared__ int   sh_src[MAXDEG];
    __shared__ float sh_p[MAXDEG * PSTRIDE];
    int n = blockIdx.x;
    int t = threadIdx.x;
    int h = t >> 5, lane32 = t & 31;
    int quad = lane32 & 7;
    int sub  = lane32 >> 3;
    int beg = row_start[n], deg = row_start[n + 1] - beg;
    float sd = s_dst[n * HEADS + h];
    float m = -1e30f, l = 0.f;
    float4 acc = {0.f, 0.f, 0.f, 0.f};

    for (int c0 = 0; c0 < deg; c0 += MAXDEG) {
        int degc = min(deg - c0, MAXDEG);
        if (t < degc) sh_src[t] = csr_src[beg + c0 + t];
        __syncthreads();

        // ---- phase A: this head's edge scores (32 lanes cover all edges) ----
        float earr[MAXDEG / 32];
        float mx = -1e30f;
        for (int i = lane32, j = 0; i < degc; i += 32, j++) {
            int s = sh_src[i];
            float e = s_src[s * HEADS + h] + sd;
            e = (e >= 0.f) ? e : 0.2f * e;           // leaky_relu(0.2)
            earr[j] = e;
            mx = fmaxf(mx, e);
        }
#pragma unroll
        for (int off = 16; off >= 1; off >>= 1) mx = fmaxf(mx, __shfl_xor(mx, off));
        float mn = fmaxf(m, mx);
        float sc = __expf(m - mn);
        float lsum = 0.f;
        for (int i = lane32, j = 0; i < degc; i += 32, j++) {
            float p = __expf(earr[j] - mn);
            sh_p[i * PSTRIDE + h] = p;
            lsum += p;
        }
#pragma unroll
        for (int off = 16; off >= 1; off >>= 1) lsum += __shfl_xor(lsum, off);
        l = l * sc + lsum;
        m = mn;
        __syncthreads();

        // ---- phase B: ushort4 gather-FMA; each thread every 4th edge ----
        float4 part = {0.f, 0.f, 0.f, 0.f};
        const unsigned short* base = xw1b + h * 32 + quad * 4;
        for (int i = sub; i < degc; i += 4) {
            int s = sh_src[i];
            float p = sh_p[i * PSTRIDE + h];
            ushort4 v = *(const ushort4*)(base + (size_t)s * C1);
            part.x += p * bf2f(v.x);
            part.y += p * bf2f(v.y);
            part.z += p * bf2f(v.z);
            part.w += p * bf2f(v.w);
        }
        acc.x = acc.x * sc + part.x;
        acc.y = acc.y * sc + part.y;
        acc.z = acc.z * sc + part.z;
        acc.w = acc.w * sc + part.w;
        __syncthreads();
    }

    // combine 4 edge subgroups (flip bits 3,4 of lane index)
#pragma unroll
    for (int off = 8; off <= 16; off <<= 1) {
        acc.x += __shfl_xor(acc.x, off);
        acc.y += __shfl_xor(acc.y, off);
        acc.z += __shfl_xor(acc.z, off);
        acc.w += __shfl_xor(acc.w, off);
    }
    if (sub == 0) {
        int c = h * 32 + quad * 4;
        float linv = 1.f / fmaxf(l, 1e-16f);
        float o0 = acc.x * linv + b1[c + 0];
        float o1 = acc.y * linv + b1[c + 1];
        float o2 = acc.z * linv + b1[c + 2];
        float o3 = acc.w * linv + b1[c + 3];
        o0 = (o0 > 0.f) ? o0 : (__expf(o0) - 1.f);
        o1 = (o1 > 0.f) ? o1 : (__expf(o1) - 1.f);
        o2 = (o2 > 0.f) ? o2 : (__expf(o2) - 1.f);
        o3 = (o3 > 0.f) ? o3 : (__expf(o3) - 1.f);
        ushort4 st = { f2bf(o0), f2bf(o1), f2bf(o2), f2bf(o3) };
        *(ushort4*)(h1b + (size_t)n * C1 + c) = st;
    }
}

// ---------------------------------------------------------------------------
// Layer 2 GEMM via MFMA bf16: xw2 = h1 @ W2 (fp32 out) + fused s2 scores
// ---------------------------------------------------------------------------
__global__ __launch_bounds__(256) void gemm2_mfma_kernel(
        const unsigned short* __restrict__ h1b, const unsigned short* __restrict__ W2p,
        const float* __restrict__ a_src, const float* __restrict__ a_dst,
        float* __restrict__ xw2, float* __restrict__ s_src2, float* __restrict__ s_dst2) {
    int wave = threadIdx.x >> 6;
    int lane = threadIdx.x & 63;
    int tile = blockIdx.x * 4 + wave;            // 16-row tile index
    if (tile >= N_NODES / 16) return;            // 1250 tiles
    int quad = lane >> 4, col = lane & 15;
    int row0 = tile * 16;

    floatx4 acc[8];
#pragma unroll
    for (int ct = 0; ct < 8; ct++) acc[ct] = (floatx4){0.f, 0.f, 0.f, 0.f};

    const bf16x8* pb = (const bf16x8*)W2p;       // [(kb*8+ct)*64 + lane]
    int m = row0 + col;                          // A-frag row for this lane
#pragma unroll
    for (int kb = 0; kb < 10; kb++) {
        bf16x8 a = *(const bf16x8*)(h1b + (size_t)m * C1 + kb * 32 + quad * 8);
#pragma unroll
        for (int ct = 0; ct < 8; ct++) {
            bf16x8 b = pb[(kb * 8 + ct) * 64 + lane];
            acc[ct] = __builtin_amdgcn_mfma_f32_16x16x32_bf16(a, b, acc[ct], 0, 0, 0);
        }
    }

    float asv[8], adv[8];
#pragma unroll
    for (int ct = 0; ct < 8; ct++) { asv[ct] = a_src[ct * 16 + col]; adv[ct] = a_dst[ct * 16 + col]; }

#pragma unroll
    for (int reg = 0; reg < 4; reg++) {
        int row = row0 + quad * 4 + reg;
        float vs = 0.f, vd = 0.f;
#pragma unroll
        for (int ct = 0; ct < 8; ct++) {
            float v = acc[ct][reg];
            xw2[(size_t)row * C2 + ct * 16 + col] = v;
            vs += v * asv[ct];
            vd += v * adv[ct];
        }
#pragma unroll
        for (int off = 8; off >= 1; off >>= 1) {
            vs += __shfl_xor(vs, off);
            vd += __shfl_xor(vd, off);
        }
        if (col == 0) { s_src2[row] = vs; s_dst2[row] = vd; }
    }
}

// ---------------------------------------------------------------------------
// Layer 2 aggregation (H=1), two-phase; phase B float4 gathers + ReLU
// thread t: quad = t&31 (channels 4*quad..+3), sub = t>>5 (edges i ≡ sub mod 4)
// ---------------------------------------------------------------------------
__global__ __launch_bounds__(128) void agg2_kernel(
        const float* __restrict__ xw2, const float* __restrict__ s_src2,
        const float* __restrict__ s_dst2, const int* __restrict__ row_start,
        const int* __restrict__ csr_src, const float* __restrict__ b2,
        float* __restrict__ x2) {
    __shared__ int   sh_src[MAXDEG];
    __shared__ float sh_p[MAXDEG];
    __shared__ float sh_bc;
    __shared__ float4 sh_red[3][32];
    int n = blockIdx.x;
    int t = threadIdx.x;   // 128
    int quad = t & 31;
    int sub  = t >> 5;
    int beg = row_start[n], deg = row_start[n + 1] - beg;
    float sd = s_dst2[n];
    float m = -1e30f, l = 0.f;
    float4 acc = {0.f, 0.f, 0.f, 0.f};

    for (int c0 = 0; c0 < deg; c0 += MAXDEG) {
        int degc = min(deg - c0, MAXDEG);
        if (t < degc) sh_src[t] = csr_src[beg + c0 + t];
        __syncthreads();

        float scv;
        if (t < 64) {   // wave 0 computes all edge weights
            float e0 = -1e30f, e1 = -1e30f;
            if (t < degc) {
                float e = s_src2[sh_src[t]] + sd;
                e0 = (e >= 0.f) ? e : 0.2f * e;
            }
            if (t + 64 < degc) {
                float e = s_src2[sh_src[t + 64]] + sd;
                e1 = (e >= 0.f) ? e : 0.2f * e;
            }
            float mx = fmaxf(e0, e1);
#pragma unroll
            for (int off = 32; off >= 1; off >>= 1) mx = fmaxf(mx, __shfl_xor(mx, off));
            float mn = fmaxf(m, mx);
            scv = __expf(m - mn);
            float p0 = (t < degc)      ? __expf(e0 - mn) : 0.f;
            float p1 = (t + 64 < degc) ? __expf(e1 - mn) : 0.f;
            if (t < degc)      sh_p[t]      = p0;
            if (t + 64 < degc) sh_p[t + 64] = p1;
            float lsum = p0 + p1;
#pragma unroll
            for (int off = 32; off >= 1; off >>= 1) lsum += __shfl_xor(lsum, off);
            l = l * scv + lsum;
            m = mn;
            if (t == 0) sh_bc = scv;
        }
        __syncthreads();
        if (t >= 64) scv = sh_bc;

        float4 part = {0.f, 0.f, 0.f, 0.f};
        const float* base = xw2 + quad * 4;
        for (int i = sub; i < degc; i += 4) {
            int s = sh_src[i];
            float p = sh_p[i];
            float4 v = *(const float4*)(base + (size_t)s * C2);
            part.x += p * v.x;
            part.y += p * v.y;
            part.z += p * v.z;
            part.w += p * v.w;
        }
        acc.x = acc.x * scv + part.x;
        acc.y = acc.y * scv + part.y;
        acc.z = acc.z * scv + part.z;
        acc.w = acc.w * scv + part.w;
        __syncthreads();
    }

    if (sub > 0) sh_red[sub - 1][quad] = acc;
    __syncthreads();
    if (sub == 0) {   // wave-0 lanes: local l is valid
        acc.x += sh_red[0][quad].x + sh_red[1][quad].x + sh_red[2][quad].x;
        acc.y += sh_red[0][quad].y + sh_red[1][quad].y + sh_red[2][quad].y;
        acc.z += sh_red[0][quad].z + sh_red[1][quad].z + sh_red[2][quad].z;
        acc.w += sh_red[0][quad].w + sh_red[1][quad].w + sh_red[2][quad].w;
        float linv = 1.f / fmaxf(l, 1e-16f);
        int c = quad * 4;
        float4 o;
        o.x = fmaxf(acc.x * linv + b2[c + 0], 0.f);
        o.y = fmaxf(acc.y * linv + b2[c + 1], 0.f);
        o.z = fmaxf(acc.z * linv + b2[c + 2], 0.f);
        o.w = fmaxf(acc.w * linv + b2[c + 3], 0.f);
        *(float4*)(x2 + (size_t)n * C2 + c) = o;
    }
}

// ---------------------------------------------------------------------------
// Main output: relu(x2 @ fc_w + fc_b)  — 32 rows/block, float4 LDS broadcasts
// ---------------------------------------------------------------------------
__global__ __launch_bounds__(128) void fc_main_kernel(
        const float* __restrict__ x2, const float* __restrict__ fc_w,
        const float* __restrict__ fc_b, float* __restrict__ out) {
    __shared__ __align__(16) float A[32 * C2];   // 16 KB
    int t = threadIdx.x;
    int n0 = blockIdx.x * 32;
    {
        const float4* src = (const float4*)(x2 + (size_t)n0 * C2);
        float4* dst = (float4*)A;
#pragma unroll
        for (int i = 0; i < 8; i++) dst[t + i * 128] = src[t + i * 128];
    }
    __syncthreads();
    float acc[32];
#pragma unroll
    for (int r = 0; r < 32; r++) acc[r] = 0.f;
    for (int k = 0; k < C2; k += 4) {
        float b0 = fc_w[(k + 0) * C2 + t];
        float b1 = fc_w[(k + 1) * C2 + t];
        float b2 = fc_w[(k + 2) * C2 + t];
        float b3 = fc_w[(k + 3) * C2 + t];
#pragma unroll
        for (int r = 0; r < 32; r++) {
            float4 a4 = *(const float4*)&A[r * C2 + k];
            acc[r] += a4.x * b0 + a4.y * b1 + a4.z * b2 + a4.w * b3;
        }
    }
    float bb = fc_b[t];
    for (int r = 0; r < 32; r++)
        out[(size_t)(n0 + r) * C2 + t] = fmaxf(acc[r] + bb, 0.f);
}

// ---------------------------------------------------------------------------
// Pooling: per-graph max over 200 nodes, then relu(pooled @ fc_w + fc_b)
// ---------------------------------------------------------------------------
__global__ void pool_kernel(const float* __restrict__ x2, float* __restrict__ pooled) {
    int g = blockIdx.x, t = threadIdx.x;   // 128
    float mx = -1e30f;
    for (int i = 0; i < PER; i++)
        mx = fmaxf(mx, x2[(size_t)(g * PER + i) * C2 + t]);
    pooled[g * C2 + t] = mx;
}

__global__ void fc_pool_kernel(const float* __restrict__ pooled, const float* __restrict__ fc_w,
                               const float* __restrict__ fc_b, float* __restrict__ outp) {
    __shared__ float A[C2];
    int g = blockIdx.x, t = threadIdx.x;
    A[t] = pooled[g * C2 + t];
    __syncthreads();
    float acc = 0.f;
    for (int k = 0; k < C2; k++) acc += A[k] * fc_w[k * C2 + t];
    outp[g * C2 + t] = fmaxf(acc + fc_b[t], 0.f);
}

// ---------------------------------------------------------------------------
extern "C" void kernel_launch(void* const* d_in, const int* in_sizes, int n_in,
                              void* d_out, int out_size, void* d_ws, size_t ws_size,
                              hipStream_t stream) {
    const float* feats = (const float*)d_in[0];
    const int*   ei    = (const int*)d_in[1];
    const float* W1  = (const float*)d_in[4];
    const float* a1s = (const float*)d_in[5];
    const float* a1d = (const float*)d_in[6];
    const float* b1  = (const float*)d_in[7];
    const float* W2  = (const float*)d_in[8];
    const float* a2s = (const float*)d_in[9];
    const float* a2d = (const float*)d_in[10];
    const float* b2  = (const float*)d_in[11];
    const float* fcw = (const float*)d_in[12];
    const float* fcb = (const float*)d_in[13];

    float* out_main = (float*)d_out;                        // [20000,128]
    float* out_pool = (float*)d_out + (size_t)N_NODES * C2; // [100,128]

    char* p = (char*)d_ws;
    auto alloc = [&](size_t bytes) {
        char* r = p;
        p += (bytes + 255) & ~(size_t)255;
        return r;
    };
    unsigned short* xw1b = (unsigned short*)alloc(sizeof(short) * (size_t)N_NODES * C1);
    unsigned short* h1b  = (unsigned short*)alloc(sizeof(short) * (size_t)N_NODES * C1);
    unsigned short* W2p  = (unsigned short*)alloc(sizeof(short) * C1 * C2);
    float* s1s    = (float*)alloc(sizeof(float) * N_NODES * HEADS);
    float* s1d    = (float*)alloc(sizeof(float) * N_NODES * HEADS);
    float* xw2    = (float*)alloc(sizeof(float) * (size_t)N_NODES * C2);
    float* s2s    = (float*)alloc(sizeof(float) * N_NODES);
    float* s2d    = (float*)alloc(sizeof(float) * N_NODES);
    float* x2     = (float*)alloc(sizeof(float) * (size_t)N_NODES * C2);
    float* pooled = (float*)alloc(sizeof(float) * NB * C2);
    int* counts   = (int*)alloc(sizeof(int) * N_NODES * 2);  // counts + cursor
    int* cursor   = counts + N_NODES;
    int* row_start = (int*)alloc(sizeof(int) * (N_NODES + 1));
    int* csr_src  = (int*)alloc(sizeof(int) * ETOT);

    hipMemsetAsync(counts, 0, sizeof(int) * N_NODES * 2, stream);

    hist_w2prep_kernel<<<HIST_BLOCKS + (C1 * C2 + 255) / 256, 256, 0, stream>>>(ei, counts, W2, W2p);
    scan_kernel<<<1, 1024, 0, stream>>>(counts, row_start);
    scatter_kernel<<<(ETOT + 255) / 256, 256, 0, stream>>>(ei, row_start, cursor, csr_src);

    gemm1_kernel<<<N_NODES / 8, C1, 0, stream>>>(feats, W1, a1s, a1d, xw1b, s1s, s1d);
    agg1_kernel<<<N_NODES, C1, 0, stream>>>(xw1b, s1s, s1d, row_start, csr_src, b1, h1b);
    gemm2_mfma_kernel<<<(N_NODES / 16 + 3) / 4, 256, 0, stream>>>(h1b, W2p, a2s, a2d, xw2, s2s, s2d);
    agg2_kernel<<<N_NODES, C2, 0, stream>>>(xw2, s2s, s2d, row_start, csr_src, b2, x2);
    fc_main_kernel<<<N_NODES / 32, C2, 0, stream>>>(x2, fcw, fcb, out_main);
    pool_kernel<<<NB, C2, 0, stream>>>(x2, pooled);
    fc_pool_kernel<<<NB, C2, 0, stream>>>(pooled, fcw, fcb, out_pool);
}

// Round 6
// 355.900 us; speedup vs baseline: 1.0175x; 1.0175x over previous
//
#include <hip/hip_runtime.h>

// Problem constants (fixed by the reference)
#define N_NODES 20000
#define N_EDGES 320000
#define ETOT    (N_EDGES + N_NODES)   // edges + self-loops = 340000
#define HEADS   10
#define F_IN    32
#define C1      (HEADS * F_IN)        // 320
#define C2      128
#define NB      100
#define PER     200

typedef __attribute__((ext_vector_type(8))) short bf16x8;   // MFMA A/B frag (4 VGPRs)
typedef __attribute__((ext_vector_type(4))) float floatx4;  // MFMA C/D frag

static __device__ __forceinline__ unsigned short f2bf(float f) {
    unsigned int u = __float_as_uint(f);
    unsigned int r = (u + 0x7fffu + ((u >> 16) & 1u)) >> 16;   // RNE
    return (unsigned short)r;
}
static __device__ __forceinline__ float bf2f(unsigned short b) {
    return __uint_as_float(((unsigned int)b) << 16);
}

// ---------------------------------------------------------------------------
// CSR histogram + W2 MFMA-fragment prep (independent work, one launch)
// ---------------------------------------------------------------------------
#define HIST_BLOCKS ((ETOT + 255) / 256)
__global__ void hist_w2prep_kernel(const int* __restrict__ ei, int* __restrict__ counts,
                                   const float* __restrict__ W2, unsigned short* __restrict__ W2p) {
    if (blockIdx.x < HIST_BLOCKS) {
        int e = blockIdx.x * 256 + threadIdx.x;
        if (e >= ETOT) return;
        int d = (e < N_EDGES) ? ei[N_EDGES + e] : (e - N_EDGES);
        atomicAdd(&counts[d], 1);
    } else {
        int o = (blockIdx.x - HIST_BLOCKS) * 256 + threadIdx.x;   // 40960 total
        if (o >= C1 * C2) return;
        int j    = o & 7;
        int lane = (o >> 3) & 63;
        int ct   = (o >> 9) & 7;
        int kb   = o >> 12;
        int k = kb * 32 + (lane >> 4) * 8 + j;
        int n = ct * 16 + (lane & 15);
        W2p[o] = f2bf(W2[k * C2 + n]);
    }
}

__global__ void scan_kernel(const int* __restrict__ counts, int* __restrict__ row_start) {
    __shared__ int sums[1024];
    int tid = threadIdx.x;
    const int per = (N_NODES + 1023) / 1024;  // 20
    int base = tid * per;
    int s = 0;
    for (int i = 0; i < per; i++) {
        int idx = base + i;
        if (idx < N_NODES) s += counts[idx];
    }
    sums[tid] = s;
    __syncthreads();
    for (int off = 1; off < 1024; off <<= 1) {
        int v = (tid >= off) ? sums[tid - off] : 0;
        __syncthreads();
        sums[tid] += v;
        __syncthreads();
    }
    int run = (tid == 0) ? 0 : sums[tid - 1];
    for (int i = 0; i < per; i++) {
        int idx = base + i;
        if (idx < N_NODES) { row_start[idx] = run; run += counts[idx]; }
    }
    if (tid == 1023) row_start[N_NODES] = run;  // = ETOT
}

__global__ void scatter_kernel(const int* __restrict__ ei, const int* __restrict__ row_start,
                               int* __restrict__ cursor, int* __restrict__ csr_src) {
    int e = blockIdx.x * blockDim.x + threadIdx.x;
    if (e >= ETOT) return;
    int s, d;
    if (e < N_EDGES) { s = ei[e]; d = ei[N_EDGES + e]; }
    else             { s = e - N_EDGES; d = s; }
    int pos = atomicAdd(&cursor[d], 1);
    csr_src[row_start[d] + pos] = s;
}

// ---------------------------------------------------------------------------
// Layer 1: xw1 = feats @ W1 (stored bf16), attention scores s_src/s_dst fp32
// ---------------------------------------------------------------------------
__global__ void gemm1_kernel(const float* __restrict__ x, const float* __restrict__ W1,
                             const float* __restrict__ a_src, const float* __restrict__ a_dst,
                             unsigned short* __restrict__ xw1b, float* __restrict__ s_src,
                             float* __restrict__ s_dst) {
    __shared__ float w[F_IN * C1];   // 40 KB
    __shared__ float xr[8][F_IN];
    int t = threadIdx.x;
    for (int i = t; i < F_IN * C1; i += C1) w[i] = W1[i];
    int n0 = blockIdx.x * 8;
    for (int i = t; i < 8 * F_IN; i += C1) {
        int r = i >> 5, c = i & 31;
        xr[r][c] = x[(n0 + r) * F_IN + c];
    }
    __syncthreads();
    int h = t >> 5, f = t & 31;
    float as = a_src[t];
    float ad = a_dst[t];
    for (int r = 0; r < 8; r++) {
        int n = n0 + r;
        float acc = 0.f;
#pragma unroll
        for (int k = 0; k < F_IN; k++) acc += xr[r][k] * w[k * C1 + t];
        xw1b[(size_t)n * C1 + t] = f2bf(acc);
        float vs = acc * as, vd = acc * ad;
#pragma unroll
        for (int off = 16; off >= 1; off >>= 1) {
            vs += __shfl_xor(vs, off);
            vd += __shfl_xor(vd, off);
        }
        if (f == 0) { s_src[n * HEADS + h] = vs; s_dst[n * HEADS + h] = vd; }
    }
}

// ---------------------------------------------------------------------------
// Layer 1 aggregation: ONE WAVE per (node, head-pair). No LDS, no barriers.
// lane = hl*32 + f; lane owns channel (2w+hl)*32+f.
// All cross-lane ops (shfl/shfl_xor) are in wave-uniform control flow;
// head selection happens on the VGPR result AFTER both shfls (no divergent
// shfl — that was round-5's UB).
// ---------------------------------------------------------------------------
__global__ __launch_bounds__(256) void agg1_kernel(
        const unsigned short* __restrict__ xw1b, const float* __restrict__ s_src,
        const float* __restrict__ s_dst, const int* __restrict__ row_start,
        const int* __restrict__ csr_src, const float* __restrict__ b1,
        unsigned short* __restrict__ h1b) {
    int wid = blockIdx.x * 4 + (threadIdx.x >> 6);   // 100000 waves total
    int lane = threadIdx.x & 63;
    int n = wid / 5;
    int w = wid - n * 5;                             // head pair: heads 2w, 2w+1
    int hl = lane >> 5;
    int f  = lane & 31;
    int cofs = (2 * w + hl) * 32 + f;                // this lane's channel
    int beg = row_start[n], deg = row_start[n + 1] - beg;
    float2 sdp = *(const float2*)(s_dst + (size_t)n * HEADS + 2 * w);
    float m0 = -1e30f, m1 = -1e30f, l0 = 0.f, l1 = 0.f, accv = 0.f;

    for (int c0 = 0; c0 < deg; c0 += 64) {
        int dc = min(deg - c0, 64);
        int srcv = 0;
        float e0 = -1e30f, e1 = -1e30f;
        if (lane < dc) {
            srcv = csr_src[beg + c0 + lane];
            float2 ss = *(const float2*)(s_src + (size_t)srcv * HEADS + 2 * w);
            e0 = ss.x + sdp.x; e0 = (e0 >= 0.f) ? e0 : 0.2f * e0;   // leaky_relu
            e1 = ss.y + sdp.y; e1 = (e1 >= 0.f) ? e1 : 0.2f * e1;
        }
        float mx0 = e0, mx1 = e1;
#pragma unroll
        for (int off = 32; off >= 1; off >>= 1) {
            mx0 = fmaxf(mx0, __shfl_xor(mx0, off));
            mx1 = fmaxf(mx1, __shfl_xor(mx1, off));
        }
        float nm0 = fmaxf(m0, mx0), nm1 = fmaxf(m1, mx1);
        float sc0 = __expf(m0 - nm0), sc1 = __expf(m1 - nm1);
        float p0 = (lane < dc) ? __expf(e0 - nm0) : 0.f;
        float p1 = (lane < dc) ? __expf(e1 - nm1) : 0.f;
        float su0 = p0, su1 = p1;
#pragma unroll
        for (int off = 32; off >= 1; off >>= 1) {
            su0 += __shfl_xor(su0, off);
            su1 += __shfl_xor(su1, off);
        }
        l0 = l0 * sc0 + su0; l1 = l1 * sc1 + su1;
        m0 = nm0; m1 = nm1;
        accv *= (hl == 0) ? sc0 : sc1;               // uniform values, VGPR select

        int groups = (dc + 7) >> 3;
        for (int g = 0; g < groups; g++) {
            int i0 = g * 8;
            float pp[8], vv[8];
#pragma unroll
            for (int j = 0; j < 8; j++) {
                int ii = i0 + j;
                int idx = (ii < dc) ? ii : (dc - 1);
                int s = __shfl(srcv, idx);           // uniform flow, all lanes
                float ph0 = __shfl(p0, idx);         // both shfls unconditional
                float ph1 = __shfl(p1, idx);
                float ph = (hl == 0) ? ph0 : ph1;    // select AFTER shfl
                pp[j] = (ii < dc) ? ph : 0.f;
                vv[j] = bf2f(xw1b[(size_t)s * C1 + cofs]);
            }
#pragma unroll
            for (int j = 0; j < 8; j++) accv += pp[j] * vv[j];
        }
    }

    float lh = (hl == 0) ? l0 : l1;
    float o = accv / fmaxf(lh, 1e-16f) + b1[cofs];
    o = (o > 0.f) ? o : (__expf(o) - 1.f);           // ELU
    h1b[(size_t)n * C1 + cofs] = f2bf(o);
}

// ---------------------------------------------------------------------------
// Layer 2 GEMM via MFMA bf16: xw2 fp32 out + fused fp32 s2 scores
// ---------------------------------------------------------------------------
__global__ __launch_bounds__(256) void gemm2_mfma_kernel(
        const unsigned short* __restrict__ h1b, const unsigned short* __restrict__ W2p,
        const float* __restrict__ a_src, const float* __restrict__ a_dst,
        float* __restrict__ xw2, float* __restrict__ s_src2, float* __restrict__ s_dst2) {
    int wave = threadIdx.x >> 6;
    int lane = threadIdx.x & 63;
    int tile = blockIdx.x * 4 + wave;            // 16-row tile index
    if (tile >= N_NODES / 16) return;            // 1250 tiles (wave-uniform exit)
    int quad = lane >> 4, col = lane & 15;
    int row0 = tile * 16;

    floatx4 acc[8];
#pragma unroll
    for (int ct = 0; ct < 8; ct++) acc[ct] = (floatx4){0.f, 0.f, 0.f, 0.f};

    const bf16x8* pb = (const bf16x8*)W2p;       // [(kb*8+ct)*64 + lane]
    int m = row0 + col;                          // A-frag row for this lane
#pragma unroll
    for (int kb = 0; kb < 10; kb++) {
        bf16x8 a = *(const bf16x8*)(h1b + (size_t)m * C1 + kb * 32 + quad * 8);
#pragma unroll
        for (int ct = 0; ct < 8; ct++) {
            bf16x8 b = pb[(kb * 8 + ct) * 64 + lane];
            acc[ct] = __builtin_amdgcn_mfma_f32_16x16x32_bf16(a, b, acc[ct], 0, 0, 0);
        }
    }

    float asv[8], adv[8];
#pragma unroll
    for (int ct = 0; ct < 8; ct++) { asv[ct] = a_src[ct * 16 + col]; adv[ct] = a_dst[ct * 16 + col]; }

#pragma unroll
    for (int reg = 0; reg < 4; reg++) {
        int row = row0 + quad * 4 + reg;
        float vs = 0.f, vd = 0.f;
#pragma unroll
        for (int ct = 0; ct < 8; ct++) {
            float v = acc[ct][reg];
            xw2[(size_t)row * C2 + ct * 16 + col] = v;
            vs += v * asv[ct];
            vd += v * adv[ct];
        }
#pragma unroll
        for (int off = 8; off >= 1; off >>= 1) {
            vs += __shfl_xor(vs, off);
            vd += __shfl_xor(vd, off);
        }
        if (col == 0) { s_src2[row] = vs; s_dst2[row] = vd; }
    }
}

// ---------------------------------------------------------------------------
// Layer 2 aggregation (H=1): ONE WAVE per node. Lane owns 2 channels (float2).
// All shfls in wave-uniform control flow.
// ---------------------------------------------------------------------------
__global__ __launch_bounds__(256) void agg2_kernel(
        const float* __restrict__ xw2, const float* __restrict__ s_src2,
        const float* __restrict__ s_dst2, const int* __restrict__ row_start,
        const int* __restrict__ csr_src, const float* __restrict__ b2,
        float* __restrict__ x2) {
    int n = blockIdx.x * 4 + (threadIdx.x >> 6);     // 20000 waves
    int lane = threadIdx.x & 63;
    int beg = row_start[n], deg = row_start[n + 1] - beg;
    float sd = s_dst2[n];
    float m = -1e30f, l = 0.f, a0 = 0.f, a1 = 0.f;

    for (int c0 = 0; c0 < deg; c0 += 64) {
        int dc = min(deg - c0, 64);
        int srcv = 0;
        float e = -1e30f;
        if (lane < dc) {
            srcv = csr_src[beg + c0 + lane];
            float t = s_src2[srcv] + sd;
            e = (t >= 0.f) ? t : 0.2f * t;
        }
        float mx = e;
#pragma unroll
        for (int off = 32; off >= 1; off >>= 1) mx = fmaxf(mx, __shfl_xor(mx, off));
        float nm = fmaxf(m, mx);
        float sc = __expf(m - nm);
        float p = (lane < dc) ? __expf(e - nm) : 0.f;
        float su = p;
#pragma unroll
        for (int off = 32; off >= 1; off >>= 1) su += __shfl_xor(su, off);
        l = l * sc + su;
        m = nm;
        a0 *= sc; a1 *= sc;

        int groups = (dc + 7) >> 3;
        for (int g = 0; g < groups; g++) {
            int i0 = g * 8;
            float pp[8]; float2 vv[8];
#pragma unroll
            for (int j = 0; j < 8; j++) {
                int ii = i0 + j;
                int idx = (ii < dc) ? ii : (dc - 1);
                int s = __shfl(srcv, idx);
                float ph = __shfl(p, idx);
                pp[j] = (ii < dc) ? ph : 0.f;
                vv[j] = *(const float2*)(xw2 + (size_t)s * C2 + 2 * lane);
            }
#pragma unroll
            for (int j = 0; j < 8; j++) {
                a0 += pp[j] * vv[j].x;
                a1 += pp[j] * vv[j].y;
            }
        }
    }

    float linv = 1.f / fmaxf(l, 1e-16f);
    float2 bb = *(const float2*)(b2 + 2 * lane);
    float2 o;
    o.x = fmaxf(a0 * linv + bb.x, 0.f);
    o.y = fmaxf(a1 * linv + bb.y, 0.f);
    *(float2*)(x2 + (size_t)n * C2 + 2 * lane) = o;   // ReLU'd, fp32
}

// ---------------------------------------------------------------------------
// Main output: relu(x2 @ fc_w + fc_b) — 16 rows/block, float4 LDS broadcasts
// ---------------------------------------------------------------------------
__global__ void fc_main_kernel(const float* __restrict__ x2, const float* __restrict__ fc_w,
                               const float* __restrict__ fc_b, float* __restrict__ out) {
    __shared__ __align__(16) float A[16 * C2];   // 8 KB
    int t = threadIdx.x;
    int n0 = blockIdx.x * 16;
    for (int i = t; i < 16 * C2; i += 128) A[i] = x2[(size_t)n0 * C2 + i];
    __syncthreads();
    float acc[16];
#pragma unroll
    for (int r = 0; r < 16; r++) acc[r] = 0.f;
    for (int k = 0; k < C2; k += 4) {
        float b0 = fc_w[(k + 0) * C2 + t];
        float b1 = fc_w[(k + 1) * C2 + t];
        float b2 = fc_w[(k + 2) * C2 + t];
        float b3 = fc_w[(k + 3) * C2 + t];
#pragma unroll
        for (int r = 0; r < 16; r++) {
            float4 a4 = *(const float4*)&A[r * C2 + k];
            acc[r] += a4.x * b0 + a4.y * b1 + a4.z * b2 + a4.w * b3;
        }
    }
    float bb = fc_b[t];
    for (int r = 0; r < 16; r++)
        out[(size_t)(n0 + r) * C2 + t] = fmaxf(acc[r] + bb, 0.f);
}

// ---------------------------------------------------------------------------
// Pooling: per-graph max over 200 nodes, then relu(pooled @ fc_w + fc_b)
// ---------------------------------------------------------------------------
__global__ void pool_kernel(const float* __restrict__ x2, float* __restrict__ pooled) {
    int g = blockIdx.x, t = threadIdx.x;   // 128
    float mx = -1e30f;
    for (int i = 0; i < PER; i++)
        mx = fmaxf(mx, x2[(size_t)(g * PER + i) * C2 + t]);
    pooled[g * C2 + t] = mx;
}

__global__ void fc_pool_kernel(const float* __restrict__ pooled, const float* __restrict__ fc_w,
                               const float* __restrict__ fc_b, float* __restrict__ outp) {
    __shared__ float A[C2];
    int g = blockIdx.x, t = threadIdx.x;
    A[t] = pooled[g * C2 + t];
    __syncthreads();
    float acc = 0.f;
    for (int k = 0; k < C2; k++) acc += A[k] * fc_w[k * C2 + t];
    outp[g * C2 + t] = fmaxf(acc + fc_b[t], 0.f);
}

// ---------------------------------------------------------------------------
extern "C" void kernel_launch(void* const* d_in, const int* in_sizes, int n_in,
                              void* d_out, int out_size, void* d_ws, size_t ws_size,
                              hipStream_t stream) {
    const float* feats = (const float*)d_in[0];
    const int*   ei    = (const int*)d_in[1];
    const float* W1  = (const float*)d_in[4];
    const float* a1s = (const float*)d_in[5];
    const float* a1d = (const float*)d_in[6];
    const float* b1  = (const float*)d_in[7];
    const float* W2  = (const float*)d_in[8];
    const float* a2s = (const float*)d_in[9];
    const float* a2d = (const float*)d_in[10];
    const float* b2  = (const float*)d_in[11];
    const float* fcw = (const float*)d_in[12];
    const float* fcb = (const float*)d_in[13];

    float* out_main = (float*)d_out;                        // [20000,128]
    float* out_pool = (float*)d_out + (size_t)N_NODES * C2; // [100,128]

    char* p = (char*)d_ws;
    auto alloc = [&](size_t bytes) {
        char* r = p;
        p += (bytes + 255) & ~(size_t)255;
        return r;
    };
    unsigned short* xw1b = (unsigned short*)alloc(sizeof(short) * (size_t)N_NODES * C1);
    unsigned short* h1b  = (unsigned short*)alloc(sizeof(short) * (size_t)N_NODES * C1);
    unsigned short* W2p  = (unsigned short*)alloc(sizeof(short) * C1 * C2);
    float* xw2    = (float*)alloc(sizeof(float) * (size_t)N_NODES * C2);
    float* s1s    = (float*)alloc(sizeof(float) * N_NODES * HEADS);
    float* s1d    = (float*)alloc(sizeof(float) * N_NODES * HEADS);
    float* s2s    = (float*)alloc(sizeof(float) * N_NODES);
    float* s2d    = (float*)alloc(sizeof(float) * N_NODES);
    float* x2     = (float*)alloc(sizeof(float) * (size_t)N_NODES * C2);
    float* pooled = (float*)alloc(sizeof(float) * NB * C2);
    int* counts   = (int*)alloc(sizeof(int) * N_NODES * 2);  // counts + cursor
    int* cursor   = counts + N_NODES;
    int* row_start = (int*)alloc(sizeof(int) * (N_NODES + 1));
    int* csr_src  = (int*)alloc(sizeof(int) * ETOT);

    hipMemsetAsync(counts, 0, sizeof(int) * N_NODES * 2, stream);

    hist_w2prep_kernel<<<HIST_BLOCKS + (C1 * C2 + 255) / 256, 256, 0, stream>>>(ei, counts, W2, W2p);
    scan_kernel<<<1, 1024, 0, stream>>>(counts, row_start);
    scatter_kernel<<<(ETOT + 255) / 256, 256, 0, stream>>>(ei, row_start, cursor, csr_src);

    gemm1_kernel<<<N_NODES / 8, C1, 0, stream>>>(feats, W1, a1s, a1d, xw1b, s1s, s1d);
    agg1_kernel<<<N_NODES * 5 / 4, 256, 0, stream>>>(xw1b, s1s, s1d, row_start, csr_src, b1, h1b);
    gemm2_mfma_kernel<<<(N_NODES / 16 + 3) / 4, 256, 0, stream>>>(h1b, W2p, a2s, a2d, xw2, s2s, s2d);
    agg2_kernel<<<N_NODES / 4, 256, 0, stream>>>(xw2, s2s, s2d, row_start, csr_src, b2, x2);
    fc_main_kernel<<<N_NODES / 16, C2, 0, stream>>>(x2, fcw, fcb, out_main);
    pool_kernel<<<NB, C2, 0, stream>>>(x2, pooled);
    fc_pool_kernel<<<NB, C2, 0, stream>>>(pooled, fcw, fcb, out_pool);
}

// Round 7
// 332.223 us; speedup vs baseline: 1.0901x; 1.0713x over previous
//
#include <hip/hip_runtime.h>

// Problem constants (fixed by the reference)
#define N_NODES 20000
#define N_EDGES 320000
#define ETOT    (N_EDGES + N_NODES)   // edges + self-loops = 340000
#define HEADS   10
#define F_IN    32
#define C1      (HEADS * F_IN)        // 320
#define C2      128
#define NB      100
#define PER     200
#define MAXDEG  128                   // chunk size for per-node edge lists
#define PSTRIDE 11                    // sh_p stride: gcd(11,32)=1 -> conflict-free

typedef __attribute__((ext_vector_type(8))) short bf16x8;   // MFMA A/B frag (4 VGPRs)
typedef __attribute__((ext_vector_type(4))) float floatx4;  // MFMA C/D frag

static __device__ __forceinline__ unsigned short f2bf(float f) {
    unsigned int u = __float_as_uint(f);
    unsigned int r = (u + 0x7fffu + ((u >> 16) & 1u)) >> 16;   // RNE
    return (unsigned short)r;
}
static __device__ __forceinline__ float bf2f(unsigned short b) {
    return __uint_as_float(((unsigned int)b) << 16);
}

// ---------------------------------------------------------------------------
// Combined prep: CSR histogram + W2 MFMA-fragment prep + W1@a1 fold (WA).
//   WAs[k*10+h] = sum_f W1[k][h*32+f] * a1_src[h][f]   (and WAd for a1_dst)
// ---------------------------------------------------------------------------
#define HIST_BLOCKS ((ETOT + 255) / 256)
#define W2P_BLOCKS  ((C1 * C2 + 255) / 256)
__global__ void prep_kernel(const int* __restrict__ ei, int* __restrict__ counts,
                            const float* __restrict__ W2, unsigned short* __restrict__ W2p,
                            const float* __restrict__ W1, const float* __restrict__ a1s,
                            const float* __restrict__ a1d,
                            float* __restrict__ WAs, float* __restrict__ WAd) {
    if (blockIdx.x < HIST_BLOCKS) {
        int e = blockIdx.x * 256 + threadIdx.x;
        if (e >= ETOT) return;
        int d = (e < N_EDGES) ? ei[N_EDGES + e] : (e - N_EDGES);
        atomicAdd(&counts[d], 1);
    } else if (blockIdx.x < HIST_BLOCKS + W2P_BLOCKS) {
        int o = (blockIdx.x - HIST_BLOCKS) * 256 + threadIdx.x;   // 40960 total
        if (o >= C1 * C2) return;
        int j    = o & 7;
        int lane = (o >> 3) & 63;
        int ct   = (o >> 9) & 7;
        int kb   = o >> 12;
        int k = kb * 32 + (lane >> 4) * 8 + j;
        int n = ct * 16 + (lane & 15);
        W2p[o] = f2bf(W2[k * C2 + n]);
    } else {
        // one block: fold attention vectors through W1. 320 outputs x2.
        int t = threadIdx.x;
        for (int o = t; o < C1; o += 256) {
            int k = o & 31, h = o >> 5;
            float ss = 0.f, dd = 0.f;
#pragma unroll
            for (int f = 0; f < F_IN; f++) {
                float wv = W1[k * C1 + h * 32 + f];
                ss += wv * a1s[h * 32 + f];
                dd += wv * a1d[h * 32 + f];
            }
            WAs[k * HEADS + h] = ss;
            WAd[k * HEADS + h] = dd;
        }
    }
}

__global__ void scan_kernel(const int* __restrict__ counts, int* __restrict__ row_start) {
    __shared__ int sums[1024];
    int tid = threadIdx.x;
    const int per = (N_NODES + 1023) / 1024;  // 20
    int base = tid * per;
    int s = 0;
    for (int i = 0; i < per; i++) {
        int idx = base + i;
        if (idx < N_NODES) s += counts[idx];
    }
    sums[tid] = s;
    __syncthreads();
    for (int off = 1; off < 1024; off <<= 1) {
        int v = (tid >= off) ? sums[tid - off] : 0;
        __syncthreads();
        sums[tid] += v;
        __syncthreads();
    }
    int run = (tid == 0) ? 0 : sums[tid - 1];
    for (int i = 0; i < per; i++) {
        int idx = base + i;
        if (idx < N_NODES) { row_start[idx] = run; run += counts[idx]; }
    }
    if (tid == 1023) row_start[N_NODES] = run;  // = ETOT
}

__global__ void scatter_kernel(const int* __restrict__ ei, const int* __restrict__ row_start,
                               int* __restrict__ cursor, int* __restrict__ csr_src) {
    int e = blockIdx.x * blockDim.x + threadIdx.x;
    if (e >= ETOT) return;
    int s, d;
    if (e < N_EDGES) { s = ei[e]; d = ei[N_EDGES + e]; }
    else             { s = e - N_EDGES; d = s; }
    int pos = atomicAdd(&cursor[d], 1);
    csr_src[row_start[d] + pos] = s;
}

// ---------------------------------------------------------------------------
// Layer-1 scores: s_src[n,h] = feats[n,:] . WAs[:,h]  (and s_dst with WAd)
// block: 256 threads, 64 nodes per block, feats rows staged in LDS
// ---------------------------------------------------------------------------
__global__ __launch_bounds__(256) void score1_kernel(
        const float* __restrict__ feats, const float* __restrict__ WAs,
        const float* __restrict__ WAd, float* __restrict__ s_src,
        float* __restrict__ s_dst) {
    __shared__ __align__(16) float A[64 * F_IN];   // 8 KB
    __shared__ float Ws[C1], Wd[C1];
    int t = threadIdx.x;
    int n0 = blockIdx.x * 64;
    int nrows = min(64, N_NODES - n0);
    for (int i = t; i < C1; i += 256) { Ws[i] = WAs[i]; Wd[i] = WAd[i]; }
    const float4* fs = (const float4*)(feats + (size_t)n0 * F_IN);
    float4* Af = (float4*)A;
    for (int i = t; i < nrows * 8; i += 256) Af[i] = fs[i];
    __syncthreads();
    for (int o = t; o < nrows * HEADS; o += 256) {
        int nl = o / HEADS, h = o - nl * HEADS;
        const float* ar = A + nl * F_IN;
        float ss = 0.f, dd = 0.f;
#pragma unroll
        for (int k = 0; k < F_IN; k++) {
            float av = ar[k];
            ss += av * Ws[k * HEADS + h];
            dd += av * Wd[k * HEADS + h];
        }
        s_src[(size_t)(n0 + nl) * HEADS + h] = ss;
        s_dst[(size_t)(n0 + nl) * HEADS + h] = dd;
    }
}

// ---------------------------------------------------------------------------
// Layer 1 aggregation via feats-gather (algebraic rewrite):
//   g[n,h,k] = sum_i alpha_{i,h} * feats[s_i, k]     (gather: 128 B/edge,
//                                                     2.56 MB working set)
//   h1[n,h,f] = ELU( (g[n,h,:]/l_h) @ W1[:, h*32+f] + b1 )
// block: 320 threads (t = h*32+k), one node per block; two-phase softmax.
// Epilogue: 32-step shfl broadcast of g + coalesced W1 reads.
// ---------------------------------------------------------------------------
__global__ __launch_bounds__(320) void agg1_kernel(
        const float* __restrict__ feats, const float* __restrict__ s_src,
        const float* __restrict__ s_dst, const int* __restrict__ row_start,
        const int* __restrict__ csr_src, const float* __restrict__ W1,
        const float* __restrict__ b1, unsigned short* __restrict__ h1b) {
    __shared__ int   sh_src[MAXDEG];
    __shared__ float sh_p[MAXDEG * PSTRIDE];
    int n = blockIdx.x;
    int t = threadIdx.x;
    int h = t >> 5, lane32 = t & 31;
    int beg = row_start[n], deg = row_start[n + 1] - beg;
    float sd = s_dst[(size_t)n * HEADS + h];
    float m = -1e30f, l = 0.f, acc = 0.f;

    for (int c0 = 0; c0 < deg; c0 += MAXDEG) {
        int degc = min(deg - c0, MAXDEG);
        if (t < degc) sh_src[t] = csr_src[beg + c0 + t];
        __syncthreads();

        // ---- phase A: this head's edge scores (32 lanes cover all edges) ----
        float earr[MAXDEG / 32];
        float mx = -1e30f;
        for (int i = lane32, j = 0; i < degc; i += 32, j++) {
            int s = sh_src[i];
            float e = s_src[(size_t)s * HEADS + h] + sd;
            e = (e >= 0.f) ? e : 0.2f * e;           // leaky_relu(0.2)
            earr[j] = e;
            mx = fmaxf(mx, e);
        }
#pragma unroll
        for (int off = 16; off >= 1; off >>= 1) mx = fmaxf(mx, __shfl_xor(mx, off));
        float mn = fmaxf(m, mx);
        float sc = __expf(m - mn);
        float lsum = 0.f;
        for (int i = lane32, j = 0; i < degc; i += 32, j++) {
            float p = __expf(earr[j] - mn);
            sh_p[i * PSTRIDE + h] = p;
            lsum += p;
        }
#pragma unroll
        for (int off = 16; off >= 1; off >>= 1) lsum += __shfl_xor(lsum, off);
        l = l * sc + lsum;
        m = mn;
        __syncthreads();

        // ---- phase B: feats gather-FMA (lane's k = lane32), 8 in flight ----
        float partial = 0.f;
        const float* basef = feats + lane32;
        int i = 0;
        for (; i + 8 <= degc; i += 8) {
            int   s0 = sh_src[i + 0], s1 = sh_src[i + 1], s2 = sh_src[i + 2], s3 = sh_src[i + 3];
            int   s4 = sh_src[i + 4], s5 = sh_src[i + 5], s6 = sh_src[i + 6], s7 = sh_src[i + 7];
            float v0 = basef[(size_t)s0 * F_IN];
            float v1 = basef[(size_t)s1 * F_IN];
            float v2 = basef[(size_t)s2 * F_IN];
            float v3 = basef[(size_t)s3 * F_IN];
            float v4 = basef[(size_t)s4 * F_IN];
            float v5 = basef[(size_t)s5 * F_IN];
            float v6 = basef[(size_t)s6 * F_IN];
            float v7 = basef[(size_t)s7 * F_IN];
            partial += sh_p[(i + 0) * PSTRIDE + h] * v0;
            partial += sh_p[(i + 1) * PSTRIDE + h] * v1;
            partial += sh_p[(i + 2) * PSTRIDE + h] * v2;
            partial += sh_p[(i + 3) * PSTRIDE + h] * v3;
            partial += sh_p[(i + 4) * PSTRIDE + h] * v4;
            partial += sh_p[(i + 5) * PSTRIDE + h] * v5;
            partial += sh_p[(i + 6) * PSTRIDE + h] * v6;
            partial += sh_p[(i + 7) * PSTRIDE + h] * v7;
        }
        for (; i < degc; i++)
            partial += sh_p[i * PSTRIDE + h] * basef[(size_t)sh_src[i] * F_IN];
        acc = acc * sc + partial;
        __syncthreads();
    }

    // ---- epilogue: out[h,f=lane32] = linv * sum_k g[h,k] * W1[k, t] ----
    // shfl source (lane64&32)+k stays within this head's 32-lane group;
    // uniform control flow, computed-index bpermute (legal).
    int lane64 = t & 63;
    int sbase = lane64 & 32;
    float linv = 1.f / fmaxf(l, 1e-16f);
    float sum = 0.f;
#pragma unroll
    for (int k = 0; k < F_IN; k++) {
        float gk = __shfl(acc, sbase + k);
        sum += gk * W1[k * C1 + t];      // coalesced: 320 lanes, consecutive
    }
    float o = sum * linv + b1[t];
    o = (o > 0.f) ? o : (__expf(o) - 1.f);           // ELU
    h1b[(size_t)n * C1 + t] = f2bf(o);
}

// ---------------------------------------------------------------------------
// Layer 2 GEMM via MFMA bf16: xw2 fp32 out + fused fp32 s2 scores
// ---------------------------------------------------------------------------
__global__ __launch_bounds__(256) void gemm2_mfma_kernel(
        const unsigned short* __restrict__ h1b, const unsigned short* __restrict__ W2p,
        const float* __restrict__ a_src, const float* __restrict__ a_dst,
        float* __restrict__ xw2, float* __restrict__ s_src2, float* __restrict__ s_dst2) {
    int wave = threadIdx.x >> 6;
    int lane = threadIdx.x & 63;
    int tile = blockIdx.x * 4 + wave;            // 16-row tile index
    if (tile >= N_NODES / 16) return;            // 1250 tiles (wave-uniform exit)
    int quad = lane >> 4, col = lane & 15;
    int row0 = tile * 16;

    floatx4 acc[8];
#pragma unroll
    for (int ct = 0; ct < 8; ct++) acc[ct] = (floatx4){0.f, 0.f, 0.f, 0.f};

    const bf16x8* pb = (const bf16x8*)W2p;       // [(kb*8+ct)*64 + lane]
    int m = row0 + col;                          // A-frag row for this lane
#pragma unroll
    for (int kb = 0; kb < 10; kb++) {
        bf16x8 a = *(const bf16x8*)(h1b + (size_t)m * C1 + kb * 32 + quad * 8);
#pragma unroll
        for (int ct = 0; ct < 8; ct++) {
            bf16x8 b = pb[(kb * 8 + ct) * 64 + lane];
            acc[ct] = __builtin_amdgcn_mfma_f32_16x16x32_bf16(a, b, acc[ct], 0, 0, 0);
        }
    }

    float asv[8], adv[8];
#pragma unroll
    for (int ct = 0; ct < 8; ct++) { asv[ct] = a_src[ct * 16 + col]; adv[ct] = a_dst[ct * 16 + col]; }

#pragma unroll
    for (int reg = 0; reg < 4; reg++) {
        int row = row0 + quad * 4 + reg;
        float vs = 0.f, vd = 0.f;
#pragma unroll
        for (int ct = 0; ct < 8; ct++) {
            float v = acc[ct][reg];
            xw2[(size_t)row * C2 + ct * 16 + col] = v;
            vs += v * asv[ct];
            vd += v * adv[ct];
        }
#pragma unroll
        for (int off = 8; off >= 1; off >>= 1) {
            vs += __shfl_xor(vs, off);
            vd += __shfl_xor(vd, off);
        }
        if (col == 0) { s_src2[row] = vs; s_dst2[row] = vd; }
    }
}

// ---------------------------------------------------------------------------
// Layer 2 aggregation (H=1): ONE WAVE per node. Lane owns 2 channels (float2).
// All shfls in wave-uniform control flow.
// ---------------------------------------------------------------------------
__global__ __launch_bounds__(256) void agg2_kernel(
        const float* __restrict__ xw2, const float* __restrict__ s_src2,
        const float* __restrict__ s_dst2, const int* __restrict__ row_start,
        const int* __restrict__ csr_src, const float* __restrict__ b2,
        float* __restrict__ x2) {
    int n = blockIdx.x * 4 + (threadIdx.x >> 6);     // 20000 waves
    int lane = threadIdx.x & 63;
    int beg = row_start[n], deg = row_start[n + 1] - beg;
    float sd = s_dst2[n];
    float m = -1e30f, l = 0.f, a0 = 0.f, a1 = 0.f;

    for (int c0 = 0; c0 < deg; c0 += 64) {
        int dc = min(deg - c0, 64);
        int srcv = 0;
        float e = -1e30f;
        if (lane < dc) {
            srcv = csr_src[beg + c0 + lane];
            float t = s_src2[srcv] + sd;
            e = (t >= 0.f) ? t : 0.2f * t;
        }
        float mx = e;
#pragma unroll
        for (int off = 32; off >= 1; off >>= 1) mx = fmaxf(mx, __shfl_xor(mx, off));
        float nm = fmaxf(m, mx);
        float sc = __expf(m - nm);
        float p = (lane < dc) ? __expf(e - nm) : 0.f;
        float su = p;
#pragma unroll
        for (int off = 32; off >= 1; off >>= 1) su += __shfl_xor(su, off);
        l = l * sc + su;
        m = nm;
        a0 *= sc; a1 *= sc;

        int groups = (dc + 7) >> 3;
        for (int g = 0; g < groups; g++) {
            int i0 = g * 8;
            float pp[8]; float2 vv[8];
#pragma unroll
            for (int j = 0; j < 8; j++) {
                int ii = i0 + j;
                int idx = (ii < dc) ? ii : (dc - 1);
                int s = __shfl(srcv, idx);
                float ph = __shfl(p, idx);
                pp[j] = (ii < dc) ? ph : 0.f;
                vv[j] = *(const float2*)(xw2 + (size_t)s * C2 + 2 * lane);
            }
#pragma unroll
            for (int j = 0; j < 8; j++) {
                a0 += pp[j] * vv[j].x;
                a1 += pp[j] * vv[j].y;
            }
        }
    }

    float linv = 1.f / fmaxf(l, 1e-16f);
    float2 bb = *(const float2*)(b2 + 2 * lane);
    float2 o;
    o.x = fmaxf(a0 * linv + bb.x, 0.f);
    o.y = fmaxf(a1 * linv + bb.y, 0.f);
    *(float2*)(x2 + (size_t)n * C2 + 2 * lane) = o;   // ReLU'd, fp32
}

// ---------------------------------------------------------------------------
// Main output: relu(x2 @ fc_w + fc_b) — 16 rows/block, float4 LDS broadcasts
// ---------------------------------------------------------------------------
__global__ void fc_main_kernel(const float* __restrict__ x2, const float* __restrict__ fc_w,
                               const float* __restrict__ fc_b, float* __restrict__ out) {
    __shared__ __align__(16) float A[16 * C2];   // 8 KB
    int t = threadIdx.x;
    int n0 = blockIdx.x * 16;
    for (int i = t; i < 16 * C2; i += 128) A[i] = x2[(size_t)n0 * C2 + i];
    __syncthreads();
    float acc[16];
#pragma unroll
    for (int r = 0; r < 16; r++) acc[r] = 0.f;
    for (int k = 0; k < C2; k += 4) {
        float b0 = fc_w[(k + 0) * C2 + t];
        float b1 = fc_w[(k + 1) * C2 + t];
        float b2 = fc_w[(k + 2) * C2 + t];
        float b3 = fc_w[(k + 3) * C2 + t];
#pragma unroll
        for (int r = 0; r < 16; r++) {
            float4 a4 = *(const float4*)&A[r * C2 + k];
            acc[r] += a4.x * b0 + a4.y * b1 + a4.z * b2 + a4.w * b3;
        }
    }
    float bb = fc_b[t];
    for (int r = 0; r < 16; r++)
        out[(size_t)(n0 + r) * C2 + t] = fmaxf(acc[r] + bb, 0.f);
}

// ---------------------------------------------------------------------------
// Pooling: per-graph max over 200 nodes, then relu(pooled @ fc_w + fc_b)
// ---------------------------------------------------------------------------
__global__ void pool_kernel(const float* __restrict__ x2, float* __restrict__ pooled) {
    int g = blockIdx.x, t = threadIdx.x;   // 128
    float mx = -1e30f;
    for (int i = 0; i < PER; i++)
        mx = fmaxf(mx, x2[(size_t)(g * PER + i) * C2 + t]);
    pooled[g * C2 + t] = mx;
}

__global__ void fc_pool_kernel(const float* __restrict__ pooled, const float* __restrict__ fc_w,
                               const float* __restrict__ fc_b, float* __restrict__ outp) {
    __shared__ float A[C2];
    int g = blockIdx.x, t = threadIdx.x;
    A[t] = pooled[g * C2 + t];
    __syncthreads();
    float acc = 0.f;
    for (int k = 0; k < C2; k++) acc += A[k] * fc_w[k * C2 + t];
    outp[g * C2 + t] = fmaxf(acc + fc_b[t], 0.f);
}

// ---------------------------------------------------------------------------
extern "C" void kernel_launch(void* const* d_in, const int* in_sizes, int n_in,
                              void* d_out, int out_size, void* d_ws, size_t ws_size,
                              hipStream_t stream) {
    const float* feats = (const float*)d_in[0];
    const int*   ei    = (const int*)d_in[1];
    const float* W1  = (const float*)d_in[4];
    const float* a1s = (const float*)d_in[5];
    const float* a1d = (const float*)d_in[6];
    const float* b1  = (const float*)d_in[7];
    const float* W2  = (const float*)d_in[8];
    const float* a2s = (const float*)d_in[9];
    const float* a2d = (const float*)d_in[10];
    const float* b2  = (const float*)d_in[11];
    const float* fcw = (const float*)d_in[12];
    const float* fcb = (const float*)d_in[13];

    float* out_main = (float*)d_out;                        // [20000,128]
    float* out_pool = (float*)d_out + (size_t)N_NODES * C2; // [100,128]

    char* p = (char*)d_ws;
    auto alloc = [&](size_t bytes) {
        char* r = p;
        p += (bytes + 255) & ~(size_t)255;
        return r;
    };
    unsigned short* h1b  = (unsigned short*)alloc(sizeof(short) * (size_t)N_NODES * C1);
    unsigned short* W2p  = (unsigned short*)alloc(sizeof(short) * C1 * C2);
    float* WAs    = (float*)alloc(sizeof(float) * C1);
    float* WAd    = (float*)alloc(sizeof(float) * C1);
    float* xw2    = (float*)alloc(sizeof(float) * (size_t)N_NODES * C2);
    float* s1s    = (float*)alloc(sizeof(float) * N_NODES * HEADS);
    float* s1d    = (float*)alloc(sizeof(float) * N_NODES * HEADS);
    float* s2s    = (float*)alloc(sizeof(float) * N_NODES);
    float* s2d    = (float*)alloc(sizeof(float) * N_NODES);
    float* x2     = (float*)alloc(sizeof(float) * (size_t)N_NODES * C2);
    float* pooled = (float*)alloc(sizeof(float) * NB * C2);
    int* counts   = (int*)alloc(sizeof(int) * N_NODES * 2);  // counts + cursor
    int* cursor   = counts + N_NODES;
    int* row_start = (int*)alloc(sizeof(int) * (N_NODES + 1));
    int* csr_src  = (int*)alloc(sizeof(int) * ETOT);

    hipMemsetAsync(counts, 0, sizeof(int) * N_NODES * 2, stream);

    prep_kernel<<<HIST_BLOCKS + W2P_BLOCKS + 1, 256, 0, stream>>>(
        ei, counts, W2, W2p, W1, a1s, a1d, WAs, WAd);
    scan_kernel<<<1, 1024, 0, stream>>>(counts, row_start);
    scatter_kernel<<<(ETOT + 255) / 256, 256, 0, stream>>>(ei, row_start, cursor, csr_src);
    score1_kernel<<<(N_NODES + 63) / 64, 256, 0, stream>>>(feats, WAs, WAd, s1s, s1d);

    agg1_kernel<<<N_NODES, C1, 0, stream>>>(feats, s1s, s1d, row_start, csr_src, W1, b1, h1b);
    gemm2_mfma_kernel<<<(N_NODES / 16 + 3) / 4, 256, 0, stream>>>(h1b, W2p, a2s, a2d, xw2, s2s, s2d);
    agg2_kernel<<<N_NODES / 4, 256, 0, stream>>>(xw2, s2s, s2d, row_start, csr_src, b2, x2);
    fc_main_kernel<<<N_NODES / 16, C2, 0, stream>>>(x2, fcw, fcb, out_main);
    pool_kernel<<<NB, C2, 0, stream>>>(x2, pooled);
    fc_pool_kernel<<<NB, C2, 0, stream>>>(pooled, fcw, fcb, out_pool);
}

// Round 8
// 277.986 us; speedup vs baseline: 1.3027x; 1.1951x over previous
//
#include <hip/hip_runtime.h>

// Problem constants (fixed by the reference)
#define N_NODES 20000
#define N_EDGES 320000
#define ETOT    (N_EDGES + N_NODES)   // edges + self-loops = 340000
#define HEADS   10
#define F_IN    32
#define C1      (HEADS * F_IN)        // 320
#define C2      128
#define NB      100
#define PER     200

typedef __attribute__((ext_vector_type(8))) short bf16x8;   // MFMA A/B frag (4 VGPRs)
typedef __attribute__((ext_vector_type(4))) float floatx4;  // MFMA C/D frag
typedef _Float16 f16;

static __device__ __forceinline__ unsigned short f2bf(float f) {
    unsigned int u = __float_as_uint(f);
    unsigned int r = (u + 0x7fffu + ((u >> 16) & 1u)) >> 16;   // RNE
    return (unsigned short)r;
}

// ---------------------------------------------------------------------------
// Combined prep: CSR histogram + W2/W1 MFMA B-frag prep + WA fold + feats->f16
// ---------------------------------------------------------------------------
#define HIST_BLOCKS ((ETOT + 255) / 256)
#define W2P_BLOCKS  ((C1 * C2 + 255) / 256)            // 160
#define W1P_BLOCKS  ((HEADS * F_IN * F_IN + 255) / 256) // 40
#define F16_BLOCKS  ((N_NODES * F_IN + 255) / 256)      // 2500
__global__ void prep_kernel(const int* __restrict__ ei, int* __restrict__ counts,
                            const float* __restrict__ W2, unsigned short* __restrict__ W2p,
                            const float* __restrict__ W1, unsigned short* __restrict__ W1p,
                            const float* __restrict__ a1s, const float* __restrict__ a1d,
                            float* __restrict__ WAs, float* __restrict__ WAd,
                            const float* __restrict__ feats, f16* __restrict__ feats16) {
    unsigned int b = blockIdx.x;
    if (b < HIST_BLOCKS) {
        int e = b * 256 + threadIdx.x;
        if (e >= ETOT) return;
        int d = (e < N_EDGES) ? ei[N_EDGES + e] : (e - N_EDGES);
        atomicAdd(&counts[d], 1);
        return;
    }
    b -= HIST_BLOCKS;
    if (b < W2P_BLOCKS) {
        int o = b * 256 + threadIdx.x;   // 40960
        if (o >= C1 * C2) return;
        int j    = o & 7;
        int lane = (o >> 3) & 63;
        int ct   = (o >> 9) & 7;
        int kb   = o >> 12;
        int k = kb * 32 + (lane >> 4) * 8 + j;
        int n = ct * 16 + (lane & 15);
        W2p[o] = f2bf(W2[k * C2 + n]);
        return;
    }
    b -= W2P_BLOCKS;
    if (b < W1P_BLOCKS) {
        // B-frag for h1 GEMM: W1p[((h*2+ct)*64+lane)*8+j] = W1[quad*8+j][h*32+ct*16+col]
        int o = b * 256 + threadIdx.x;   // 10240
        if (o >= HEADS * F_IN * F_IN) return;
        int j    = o & 7;
        int lane = (o >> 3) & 63;
        int ct   = (o >> 9) & 1;
        int h    = o >> 10;
        int k = (lane >> 4) * 8 + j;
        int f = ct * 16 + (lane & 15);
        W1p[o] = f2bf(W1[k * C1 + h * 32 + f]);
        return;
    }
    b -= W1P_BLOCKS;
    if (b < F16_BLOCKS) {
        int o = b * 256 + threadIdx.x;
        if (o < N_NODES * F_IN) feats16[o] = (f16)feats[o];
        return;
    }
    // one block: fold attention vectors through W1 -> WAs/WAd [32][10]
    int t = threadIdx.x;
    for (int o = t; o < C1; o += 256) {
        int k = o & 31, h = o >> 5;
        float ss = 0.f, dd = 0.f;
#pragma unroll
        for (int f = 0; f < F_IN; f++) {
            float wv = W1[k * C1 + h * 32 + f];
            ss += wv * a1s[h * 32 + f];
            dd += wv * a1d[h * 32 + f];
        }
        WAs[k * HEADS + h] = ss;
        WAd[k * HEADS + h] = dd;
    }
}

__global__ void scan_kernel(const int* __restrict__ counts, int* __restrict__ row_start) {
    __shared__ int sums[1024];
    int tid = threadIdx.x;
    const int per = (N_NODES + 1023) / 1024;  // 20
    int base = tid * per;
    int s = 0;
    for (int i = 0; i < per; i++) {
        int idx = base + i;
        if (idx < N_NODES) s += counts[idx];
    }
    sums[tid] = s;
    __syncthreads();
    for (int off = 1; off < 1024; off <<= 1) {
        int v = (tid >= off) ? sums[tid - off] : 0;
        __syncthreads();
        sums[tid] += v;
        __syncthreads();
    }
    int run = (tid == 0) ? 0 : sums[tid - 1];
    for (int i = 0; i < per; i++) {
        int idx = base + i;
        if (idx < N_NODES) { row_start[idx] = run; run += counts[idx]; }
    }
    if (tid == 1023) row_start[N_NODES] = run;  // = ETOT
}

// ---------------------------------------------------------------------------
// Fused: CSR scatter + layer-1 scores (independent work)
//   s_src[n,h] = feats[n,:] . WAs[:,h]   (WAd for s_dst)
// ---------------------------------------------------------------------------
#define SCAT_BLOCKS ((ETOT + 255) / 256)
__global__ __launch_bounds__(256) void scatter_score_kernel(
        const int* __restrict__ ei, const int* __restrict__ row_start,
        int* __restrict__ cursor, int* __restrict__ csr_src,
        const float* __restrict__ feats, const float* __restrict__ WAs,
        const float* __restrict__ WAd, float* __restrict__ s_src,
        float* __restrict__ s_dst) {
    if (blockIdx.x < SCAT_BLOCKS) {
        int e = blockIdx.x * 256 + threadIdx.x;
        if (e >= ETOT) return;
        int s, d;
        if (e < N_EDGES) { s = ei[e]; d = ei[N_EDGES + e]; }
        else             { s = e - N_EDGES; d = s; }
        int pos = atomicAdd(&cursor[d], 1);
        csr_src[row_start[d] + pos] = s;
        return;
    }
    __shared__ __align__(16) float A[64 * F_IN];   // 8 KB
    __shared__ float Ws[C1], Wd[C1];
    int t = threadIdx.x;
    int n0 = (blockIdx.x - SCAT_BLOCKS) * 64;
    int nrows = min(64, N_NODES - n0);
    if (nrows <= 0) return;
    for (int i = t; i < C1; i += 256) { Ws[i] = WAs[i]; Wd[i] = WAd[i]; }
    const float4* fs = (const float4*)(feats + (size_t)n0 * F_IN);
    float4* Af = (float4*)A;
    for (int i = t; i < nrows * 8; i += 256) Af[i] = fs[i];
    __syncthreads();
    for (int o = t; o < nrows * HEADS; o += 256) {
        int nl = o / HEADS, h = o - nl * HEADS;
        const float* ar = A + nl * F_IN;
        float ss = 0.f, dd = 0.f;
#pragma unroll
        for (int k = 0; k < F_IN; k++) {
            float av = ar[k];
            ss += av * Ws[k * HEADS + h];
            dd += av * Wd[k * HEADS + h];
        }
        s_src[(size_t)(n0 + nl) * HEADS + h] = ss;
        s_dst[(size_t)(n0 + nl) * HEADS + h] = dd;
    }
}

// ---------------------------------------------------------------------------
// Layer-1 gather: gn[n,h,k] = (sum_e p_eh * feats[s_e,k]) / l_h   (bf16 out)
// No max-subtraction (scores bounded); ONE WAVE per node, 2 nodes per wave.
// lane = half*32 + k. Edge scores: lane e holds p[0..9] for its edge; value
// loop broadcasts (s,p) via wave-uniform-flow shfl, 2 edge-pairs per step.
// ---------------------------------------------------------------------------
__global__ __launch_bounds__(256) void aggg1_kernel(
        const f16* __restrict__ feats16, const float* __restrict__ s_src,
        const float* __restrict__ s_dst, const int* __restrict__ row_start,
        const int* __restrict__ csr_src, unsigned short* __restrict__ gn) {
    int wv = blockIdx.x * 4 + (threadIdx.x >> 6);     // 10000 waves
    int lane = threadIdx.x & 63;
    int k = lane & 31, half = lane >> 5;
#pragma unroll
    for (int rep = 0; rep < 2; rep++) {
        int n = wv + rep * 10000;
        int beg = row_start[n], deg = row_start[n + 1] - beg;
        const float* sdp = s_dst + (size_t)n * HEADS;
        float sd[10];
#pragma unroll
        for (int q = 0; q < 5; q++) {
            float2 v = *(const float2*)(sdp + 2 * q);
            sd[2 * q] = v.x; sd[2 * q + 1] = v.y;
        }
        float g[10], la[10];
#pragma unroll
        for (int h = 0; h < 10; h++) { g[h] = 0.f; la[h] = 0.f; }

        for (int c0 = 0; c0 < deg; c0 += 64) {
            int dc = min(deg - c0, 64);
            bool act = lane < dc;
            int s_e = csr_src[beg + c0 + min(lane, dc - 1)];
            const float* ssp = s_src + (size_t)s_e * HEADS;
            float p[10];
#pragma unroll
            for (int q = 0; q < 5; q++) {
                float2 v = *(const float2*)(ssp + 2 * q);
                float e0 = v.x + sd[2 * q];
                float e1 = v.y + sd[2 * q + 1];
                e0 = (e0 >= 0.f) ? e0 : 0.2f * e0;
                e1 = (e1 >= 0.f) ? e1 : 0.2f * e1;
                p[2 * q]     = act ? __expf(e0) : 0.f;
                p[2 * q + 1] = act ? __expf(e1) : 0.f;
            }
            int pairs = (dc + 1) >> 1;
            for (int j = 0; j < pairs; j += 2) {
                int e0 = 2 * j + half;
                int e1 = 2 * (j + 1) + half;
                int i0 = min(e0, dc - 1);
                int i1 = min(e1, dc - 1);
                int s0 = __shfl(s_e, i0);
                int s1 = __shfl(s_e, i1);
                float v0 = (float)feats16[(size_t)s0 * F_IN + k];
                float v1 = (float)feats16[(size_t)s1 * F_IN + k];
                bool m1ok = (j + 1 < pairs) && (e1 < dc);
                bool m0ok = (e0 < dc);
#pragma unroll
                for (int h = 0; h < 10; h++) {
                    float p0 = __shfl(p[h], i0);
                    float p1 = __shfl(p[h], i1);
                    p0 = m0ok ? p0 : 0.f;
                    p1 = m1ok ? p1 : 0.f;
                    g[h] += p0 * v0 + p1 * v1;
                    la[h] += p0 + p1;
                }
            }
        }
#pragma unroll
        for (int h = 0; h < 10; h++) {
            g[h]  += __shfl_xor(g[h], 32);
            la[h] += __shfl_xor(la[h], 32);
        }
        if (half == 0) {
            unsigned short* gp = gn + (size_t)n * C1 + k;
#pragma unroll
            for (int h = 0; h < 10; h++)
                gp[h * 32] = f2bf(g[h] / fmaxf(la[h], 1e-16f));
        }
    }
}

// ---------------------------------------------------------------------------
// h1 = ELU(gn @ W1 (per-head 32x32) + b1), bf16 out. MFMA 16x16x32.
// wave-unit = (16-row tile, head): 1250*10 = 12500 units.
// ---------------------------------------------------------------------------
__global__ __launch_bounds__(256) void h1_mfma_kernel(
        const unsigned short* __restrict__ gn, const unsigned short* __restrict__ W1p,
        const float* __restrict__ b1, unsigned short* __restrict__ h1b) {
    int unit = blockIdx.x * 4 + (threadIdx.x >> 6);
    if (unit >= 1250 * HEADS) return;
    int lane = threadIdx.x & 63;
    int tile = unit / HEADS;
    int h = unit - tile * HEADS;
    int quad = lane >> 4, col = lane & 15;
    int row0 = tile * 16;

    bf16x8 a = *(const bf16x8*)(gn + (size_t)(row0 + col) * C1 + h * 32 + quad * 8);
    bf16x8 bA = ((const bf16x8*)W1p)[(h * 2 + 0) * 64 + lane];
    bf16x8 bB = ((const bf16x8*)W1p)[(h * 2 + 1) * 64 + lane];
    floatx4 z = {0.f, 0.f, 0.f, 0.f};
    floatx4 c0 = __builtin_amdgcn_mfma_f32_16x16x32_bf16(a, bA, z, 0, 0, 0);
    floatx4 c1 = __builtin_amdgcn_mfma_f32_16x16x32_bf16(a, bB, z, 0, 0, 0);

    float bias0 = b1[h * 32 + col];
    float bias1 = b1[h * 32 + 16 + col];
#pragma unroll
    for (int reg = 0; reg < 4; reg++) {
        int row = row0 + quad * 4 + reg;
        float o0 = c0[reg] + bias0;
        float o1 = c1[reg] + bias1;
        o0 = (o0 > 0.f) ? o0 : (__expf(o0) - 1.f);
        o1 = (o1 > 0.f) ? o1 : (__expf(o1) - 1.f);
        h1b[(size_t)row * C1 + h * 32 + col]      = f2bf(o0);
        h1b[(size_t)row * C1 + h * 32 + 16 + col] = f2bf(o1);
    }
}

// ---------------------------------------------------------------------------
// Layer 2 GEMM via MFMA bf16: xw2 (fp16 out) + fused fp32 s2 scores
// ---------------------------------------------------------------------------
__global__ __launch_bounds__(256) void gemm2_mfma_kernel(
        const unsigned short* __restrict__ h1b, const unsigned short* __restrict__ W2p,
        const float* __restrict__ a_src, const float* __restrict__ a_dst,
        f16* __restrict__ xw2h, float* __restrict__ s_src2, float* __restrict__ s_dst2) {
    int wave = threadIdx.x >> 6;
    int lane = threadIdx.x & 63;
    int tile = blockIdx.x * 4 + wave;            // 16-row tile index
    if (tile >= N_NODES / 16) return;            // 1250 tiles (wave-uniform exit)
    int quad = lane >> 4, col = lane & 15;
    int row0 = tile * 16;

    floatx4 acc[8];
#pragma unroll
    for (int ct = 0; ct < 8; ct++) acc[ct] = (floatx4){0.f, 0.f, 0.f, 0.f};

    const bf16x8* pb = (const bf16x8*)W2p;       // [(kb*8+ct)*64 + lane]
    int m = row0 + col;                          // A-frag row for this lane
#pragma unroll
    for (int kb = 0; kb < 10; kb++) {
        bf16x8 a = *(const bf16x8*)(h1b + (size_t)m * C1 + kb * 32 + quad * 8);
#pragma unroll
        for (int ct = 0; ct < 8; ct++) {
            bf16x8 b = pb[(kb * 8 + ct) * 64 + lane];
            acc[ct] = __builtin_amdgcn_mfma_f32_16x16x32_bf16(a, b, acc[ct], 0, 0, 0);
        }
    }

    float asv[8], adv[8];
#pragma unroll
    for (int ct = 0; ct < 8; ct++) { asv[ct] = a_src[ct * 16 + col]; adv[ct] = a_dst[ct * 16 + col]; }

#pragma unroll
    for (int reg = 0; reg < 4; reg++) {
        int row = row0 + quad * 4 + reg;
        float vs = 0.f, vd = 0.f;
#pragma unroll
        for (int ct = 0; ct < 8; ct++) {
            float v = acc[ct][reg];
            xw2h[(size_t)row * C2 + ct * 16 + col] = (f16)v;
            vs += v * asv[ct];
            vd += v * adv[ct];
        }
#pragma unroll
        for (int off = 8; off >= 1; off >>= 1) {
            vs += __shfl_xor(vs, off);
            vd += __shfl_xor(vd, off);
        }
        if (col == 0) { s_src2[row] = vs; s_dst2[row] = vd; }
    }
}

// ---------------------------------------------------------------------------
// Layer 2 aggregation (H=1): wave per node, 2 nodes/wave, no max-subtract.
// Lane owns 2 channels (f16x2 gather). All shfls in wave-uniform flow.
// ---------------------------------------------------------------------------
__global__ __launch_bounds__(256) void agg2_kernel(
        const f16* __restrict__ xw2h, const float* __restrict__ s_src2,
        const float* __restrict__ s_dst2, const int* __restrict__ row_start,
        const int* __restrict__ csr_src, const float* __restrict__ b2,
        float* __restrict__ x2) {
    int wv = blockIdx.x * 4 + (threadIdx.x >> 6);     // 10000 waves
    int lane = threadIdx.x & 63;
#pragma unroll
    for (int rep = 0; rep < 2; rep++) {
        int n = wv + rep * 10000;
        int beg = row_start[n], deg = row_start[n + 1] - beg;
        float sd = s_dst2[n];
        float l = 0.f, a0 = 0.f, a1 = 0.f;

        for (int c0 = 0; c0 < deg; c0 += 64) {
            int dc = min(deg - c0, 64);
            bool act = lane < dc;
            int s_e = csr_src[beg + c0 + min(lane, dc - 1)];
            float e = s_src2[s_e] + sd;
            e = (e >= 0.f) ? e : 0.2f * e;
            float p = act ? __expf(e) : 0.f;
            float su = p;
#pragma unroll
            for (int off = 32; off >= 1; off >>= 1) su += __shfl_xor(su, off);
            l += su;

            int groups = (dc + 7) >> 3;
            for (int g = 0; g < groups; g++) {
                int i0 = g * 8;
                float pp[8]; float2 vv[8];
#pragma unroll
                for (int j = 0; j < 8; j++) {
                    int ii = i0 + j;
                    int idx = min(ii, dc - 1);
                    int s = __shfl(s_e, idx);
                    float ph = __shfl(p, idx);
                    pp[j] = (ii < dc) ? ph : 0.f;
                    typedef _Float16 f16x2 __attribute__((ext_vector_type(2)));
                    f16x2 hv = *(const f16x2*)(xw2h + (size_t)s * C2 + 2 * lane);
                    vv[j].x = (float)hv.x;
                    vv[j].y = (float)hv.y;
                }
#pragma unroll
                for (int j = 0; j < 8; j++) {
                    a0 += pp[j] * vv[j].x;
                    a1 += pp[j] * vv[j].y;
                }
            }
        }

        float linv = 1.f / fmaxf(l, 1e-16f);
        float2 bb = *(const float2*)(b2 + 2 * lane);
        float2 o;
        o.x = fmaxf(a0 * linv + bb.x, 0.f);
        o.y = fmaxf(a1 * linv + bb.y, 0.f);
        *(float2*)(x2 + (size_t)n * C2 + 2 * lane) = o;   // ReLU'd, fp32
    }
}

// ---------------------------------------------------------------------------
// Main output: relu(x2 @ fc_w + fc_b) — 16 rows/block, float4 LDS broadcasts
// ---------------------------------------------------------------------------
__global__ void fc_main_kernel(const float* __restrict__ x2, const float* __restrict__ fc_w,
                               const float* __restrict__ fc_b, float* __restrict__ out) {
    __shared__ __align__(16) float A[16 * C2];   // 8 KB
    int t = threadIdx.x;
    int n0 = blockIdx.x * 16;
    for (int i = t; i < 16 * C2; i += 128) A[i] = x2[(size_t)n0 * C2 + i];
    __syncthreads();
    float acc[16];
#pragma unroll
    for (int r = 0; r < 16; r++) acc[r] = 0.f;
    for (int k = 0; k < C2; k += 4) {
        float b0 = fc_w[(k + 0) * C2 + t];
        float b1 = fc_w[(k + 1) * C2 + t];
        float b2 = fc_w[(k + 2) * C2 + t];
        float b3 = fc_w[(k + 3) * C2 + t];
#pragma unroll
        for (int r = 0; r < 16; r++) {
            float4 a4 = *(const float4*)&A[r * C2 + k];
            acc[r] += a4.x * b0 + a4.y * b1 + a4.z * b2 + a4.w * b3;
        }
    }
    float bb = fc_b[t];
    for (int r = 0; r < 16; r++)
        out[(size_t)(n0 + r) * C2 + t] = fmaxf(acc[r] + bb, 0.f);
}

// ---------------------------------------------------------------------------
// Fused pooling + fc: per-graph max over 200 nodes then relu(mx @ fc_w + fc_b)
// ---------------------------------------------------------------------------
__global__ void pool_fc_kernel(const float* __restrict__ x2, const float* __restrict__ fc_w,
                               const float* __restrict__ fc_b, float* __restrict__ outp) {
    __shared__ float mx[C2];
    int g = blockIdx.x, t = threadIdx.x;   // 128
    float m = -1e30f;
    for (int i = 0; i < PER; i++)
        m = fmaxf(m, x2[(size_t)(g * PER + i) * C2 + t]);
    mx[t] = m;
    __syncthreads();
    float acc = 0.f;
    for (int k = 0; k < C2; k++) acc += mx[k] * fc_w[k * C2 + t];
    outp[g * C2 + t] = fmaxf(acc + fc_b[t], 0.f);
}

// ---------------------------------------------------------------------------
extern "C" void kernel_launch(void* const* d_in, const int* in_sizes, int n_in,
                              void* d_out, int out_size, void* d_ws, size_t ws_size,
                              hipStream_t stream) {
    const float* feats = (const float*)d_in[0];
    const int*   ei    = (const int*)d_in[1];
    const float* W1  = (const float*)d_in[4];
    const float* a1s = (const float*)d_in[5];
    const float* a1d = (const float*)d_in[6];
    const float* b1  = (const float*)d_in[7];
    const float* W2  = (const float*)d_in[8];
    const float* a2s = (const float*)d_in[9];
    const float* a2d = (const float*)d_in[10];
    const float* b2  = (const float*)d_in[11];
    const float* fcw = (const float*)d_in[12];
    const float* fcb = (const float*)d_in[13];

    float* out_main = (float*)d_out;                        // [20000,128]
    float* out_pool = (float*)d_out + (size_t)N_NODES * C2; // [100,128]

    char* p = (char*)d_ws;
    auto alloc = [&](size_t bytes) {
        char* r = p;
        p += (bytes + 255) & ~(size_t)255;
        return r;
    };
    unsigned short* gn   = (unsigned short*)alloc(sizeof(short) * (size_t)N_NODES * C1);
    unsigned short* h1b  = (unsigned short*)alloc(sizeof(short) * (size_t)N_NODES * C1);
    unsigned short* W2p  = (unsigned short*)alloc(sizeof(short) * C1 * C2);
    unsigned short* W1p  = (unsigned short*)alloc(sizeof(short) * HEADS * F_IN * F_IN);
    f16*   feats16 = (f16*)alloc(sizeof(f16) * (size_t)N_NODES * F_IN);
    f16*   xw2h    = (f16*)alloc(sizeof(f16) * (size_t)N_NODES * C2);
    float* WAs    = (float*)alloc(sizeof(float) * C1);
    float* WAd    = (float*)alloc(sizeof(float) * C1);
    float* s1s    = (float*)alloc(sizeof(float) * N_NODES * HEADS);
    float* s1d    = (float*)alloc(sizeof(float) * N_NODES * HEADS);
    float* s2s    = (float*)alloc(sizeof(float) * N_NODES);
    float* s2d    = (float*)alloc(sizeof(float) * N_NODES);
    float* x2     = (float*)alloc(sizeof(float) * (size_t)N_NODES * C2);
    int* counts   = (int*)alloc(sizeof(int) * N_NODES * 2);  // counts + cursor
    int* cursor   = counts + N_NODES;
    int* row_start = (int*)alloc(sizeof(int) * (N_NODES + 1));
    int* csr_src  = (int*)alloc(sizeof(int) * ETOT);

    hipMemsetAsync(counts, 0, sizeof(int) * N_NODES * 2, stream);

    prep_kernel<<<HIST_BLOCKS + W2P_BLOCKS + W1P_BLOCKS + F16_BLOCKS + 1, 256, 0, stream>>>(
        ei, counts, W2, W2p, W1, W1p, a1s, a1d, WAs, WAd, feats, feats16);
    scan_kernel<<<1, 1024, 0, stream>>>(counts, row_start);
    scatter_score_kernel<<<SCAT_BLOCKS + (N_NODES + 63) / 64, 256, 0, stream>>>(
        ei, row_start, cursor, csr_src, feats, WAs, WAd, s1s, s1d);

    aggg1_kernel<<<2500, 256, 0, stream>>>(feats16, s1s, s1d, row_start, csr_src, gn);
    h1_mfma_kernel<<<(1250 * HEADS + 3) / 4, 256, 0, stream>>>(gn, W1p, b1, h1b);
    gemm2_mfma_kernel<<<(N_NODES / 16 + 3) / 4, 256, 0, stream>>>(h1b, W2p, a2s, a2d, xw2h, s2s, s2d);
    agg2_kernel<<<2500, 256, 0, stream>>>(xw2h, s2s, s2d, row_start, csr_src, b2, x2);
    fc_main_kernel<<<N_NODES / 16, C2, 0, stream>>>(x2, fcw, fcb, out_main);
    pool_fc_kernel<<<NB, C2, 0, stream>>>(x2, fcw, fcb, out_pool);
}

// Round 9
// 255.157 us; speedup vs baseline: 1.4193x; 1.0895x over previous
//
#include <hip/hip_runtime.h>

// Problem constants (fixed by the reference)
#define N_NODES 20000
#define N_EDGES 320000
#define ETOT    (N_EDGES + N_NODES)   // edges + self-loops = 340000
#define HEADS   10
#define F_IN    32
#define C1      (HEADS * F_IN)        // 320
#define C2      128
#define NB      100
#define PER     200

typedef __attribute__((ext_vector_type(8))) short bf16x8;   // MFMA A/B frag (4 VGPRs)
typedef __attribute__((ext_vector_type(4))) float floatx4;  // MFMA C/D frag
typedef _Float16 f16;
typedef _Float16 f16x2 __attribute__((ext_vector_type(2)));
typedef _Float16 f16x8 __attribute__((ext_vector_type(8)));

static __device__ __forceinline__ unsigned short f2bf(float f) {
    unsigned int u = __float_as_uint(f);
    unsigned int r = (u + 0x7fffu + ((u >> 16) & 1u)) >> 16;   // RNE
    return (unsigned short)r;
}

// ---------------------------------------------------------------------------
// Combined prep: CSR histogram + W2/W1/FC MFMA B-frag prep + WA fold + feats->f16
// ---------------------------------------------------------------------------
#define HIST_BLOCKS ((ETOT + 255) / 256)
#define W2P_BLOCKS  ((C1 * C2 + 255) / 256)             // 160
#define W1P_BLOCKS  ((HEADS * F_IN * F_IN + 255) / 256) // 40
#define F16_BLOCKS  ((N_NODES * F_IN + 255) / 256)      // 2500
#define FCP_BLOCKS  ((C2 * C2 + 255) / 256)             // 64
__global__ void prep_kernel(const int* __restrict__ ei, int* __restrict__ counts,
                            const float* __restrict__ W2, unsigned short* __restrict__ W2p,
                            const float* __restrict__ W1, unsigned short* __restrict__ W1p,
                            const float* __restrict__ fcw, f16* __restrict__ FCp,
                            const float* __restrict__ a1s, const float* __restrict__ a1d,
                            float* __restrict__ WAs, float* __restrict__ WAd,
                            const float* __restrict__ feats, f16* __restrict__ feats16) {
    unsigned int b = blockIdx.x;
    if (b < HIST_BLOCKS) {
        int e = b * 256 + threadIdx.x;
        if (e >= ETOT) return;
        int d = (e < N_EDGES) ? ei[N_EDGES + e] : (e - N_EDGES);
        atomicAdd(&counts[d], 1);
        return;
    }
    b -= HIST_BLOCKS;
    if (b < W2P_BLOCKS) {
        int o = b * 256 + threadIdx.x;   // 40960
        if (o >= C1 * C2) return;
        int j    = o & 7;
        int lane = (o >> 3) & 63;
        int ct   = (o >> 9) & 7;
        int kb   = o >> 12;
        int k = kb * 32 + (lane >> 4) * 8 + j;
        int n = ct * 16 + (lane & 15);
        W2p[o] = f2bf(W2[k * C2 + n]);
        return;
    }
    b -= W2P_BLOCKS;
    if (b < W1P_BLOCKS) {
        // B-frag for h1 GEMM: W1p[((h*2+ct)*64+lane)*8+j] = W1[quad*8+j][h*32+ct*16+col]
        int o = b * 256 + threadIdx.x;   // 10240
        if (o >= HEADS * F_IN * F_IN) return;
        int j    = o & 7;
        int lane = (o >> 3) & 63;
        int ct   = (o >> 9) & 1;
        int h    = o >> 10;
        int k = (lane >> 4) * 8 + j;
        int f = ct * 16 + (lane & 15);
        W1p[o] = f2bf(W1[k * C1 + h * 32 + f]);
        return;
    }
    b -= W1P_BLOCKS;
    if (b < FCP_BLOCKS) {
        // B-frag (f16) for fc GEMM, K=128: kb<4, ct<8
        int o = b * 256 + threadIdx.x;   // 16384
        if (o >= C2 * C2) return;
        int j    = o & 7;
        int lane = (o >> 3) & 63;
        int ct   = (o >> 9) & 7;
        int kb   = o >> 12;
        int k = kb * 32 + (lane >> 4) * 8 + j;
        int n = ct * 16 + (lane & 15);
        FCp[o] = (f16)fcw[k * C2 + n];
        return;
    }
    b -= FCP_BLOCKS;
    if (b < F16_BLOCKS) {
        int o = b * 256 + threadIdx.x;
        if (o < N_NODES * F_IN) feats16[o] = (f16)feats[o];
        return;
    }
    // one block: fold attention vectors through W1 -> WAs/WAd [32][10]
    int t = threadIdx.x;
    for (int o = t; o < C1; o += 256) {
        int k = o & 31, h = o >> 5;
        float ss = 0.f, dd = 0.f;
#pragma unroll
        for (int f = 0; f < F_IN; f++) {
            float wv = W1[k * C1 + h * 32 + f];
            ss += wv * a1s[h * 32 + f];
            dd += wv * a1d[h * 32 + f];
        }
        WAs[k * HEADS + h] = ss;
        WAd[k * HEADS + h] = dd;
    }
}

__global__ void scan_kernel(const int* __restrict__ counts, int* __restrict__ row_start) {
    __shared__ int sums[1024];
    int tid = threadIdx.x;
    const int per = (N_NODES + 1023) / 1024;  // 20
    int base = tid * per;
    int s = 0;
    for (int i = 0; i < per; i++) {
        int idx = base + i;
        if (idx < N_NODES) s += counts[idx];
    }
    sums[tid] = s;
    __syncthreads();
    for (int off = 1; off < 1024; off <<= 1) {
        int v = (tid >= off) ? sums[tid - off] : 0;
        __syncthreads();
        sums[tid] += v;
        __syncthreads();
    }
    int run = (tid == 0) ? 0 : sums[tid - 1];
    for (int i = 0; i < per; i++) {
        int idx = base + i;
        if (idx < N_NODES) { row_start[idx] = run; run += counts[idx]; }
    }
    if (tid == 1023) row_start[N_NODES] = run;  // = ETOT
}

// ---------------------------------------------------------------------------
// Fused: CSR scatter + layer-1 scores (independent work)
//   s_src[n,h] = feats[n,:] . WAs[:,h]   (WAd for s_dst)
// ---------------------------------------------------------------------------
#define SCAT_BLOCKS ((ETOT + 255) / 256)
__global__ __launch_bounds__(256) void scatter_score_kernel(
        const int* __restrict__ ei, const int* __restrict__ row_start,
        int* __restrict__ cursor, int* __restrict__ csr_src,
        const float* __restrict__ feats, const float* __restrict__ WAs,
        const float* __restrict__ WAd, float* __restrict__ s_src,
        float* __restrict__ s_dst) {
    if (blockIdx.x < SCAT_BLOCKS) {
        int e = blockIdx.x * 256 + threadIdx.x;
        if (e >= ETOT) return;
        int s, d;
        if (e < N_EDGES) { s = ei[e]; d = ei[N_EDGES + e]; }
        else             { s = e - N_EDGES; d = s; }
        int pos = atomicAdd(&cursor[d], 1);
        csr_src[row_start[d] + pos] = s;
        return;
    }
    __shared__ __align__(16) float A[64 * F_IN];   // 8 KB
    __shared__ float Ws[C1], Wd[C1];
    int t = threadIdx.x;
    int n0 = (blockIdx.x - SCAT_BLOCKS) * 64;
    int nrows = min(64, N_NODES - n0);
    if (nrows <= 0) return;
    for (int i = t; i < C1; i += 256) { Ws[i] = WAs[i]; Wd[i] = WAd[i]; }
    const float4* fs = (const float4*)(feats + (size_t)n0 * F_IN);
    float4* Af = (float4*)A;
    for (int i = t; i < nrows * 8; i += 256) Af[i] = fs[i];
    __syncthreads();
    for (int o = t; o < nrows * HEADS; o += 256) {
        int nl = o / HEADS, h = o - nl * HEADS;
        const float* ar = A + nl * F_IN;
        float ss = 0.f, dd = 0.f;
#pragma unroll
        for (int k = 0; k < F_IN; k++) {
            float av = ar[k];
            ss += av * Ws[k * HEADS + h];
            dd += av * Wd[k * HEADS + h];
        }
        s_src[(size_t)(n0 + nl) * HEADS + h] = ss;
        s_dst[(size_t)(n0 + nl) * HEADS + h] = dd;
    }
}

// ---------------------------------------------------------------------------
// Layer-1 gather: gn[n,h,k] = (sum_e p_eh * feats[s_e,k]) / l_h   (bf16 out)
// ONE WAVE per node (2 nodes/wave serial). No block barriers.
// Per chunk: lane e computes p[10] for its edge, writes to its private LDS
// row (48B stride); value loop reads (s, p[0..9]) via 2-address broadcast
// LDS reads (2-way = conflict-free). Intra-wave round-trip fenced by
// s_waitcnt lgkmcnt(0). Pad rows (p=0) make the loop branch-free.
// ---------------------------------------------------------------------------
__global__ __launch_bounds__(256) void aggg1_kernel(
        const f16* __restrict__ feats16, const float* __restrict__ s_src,
        const float* __restrict__ s_dst, const int* __restrict__ row_start,
        const int* __restrict__ csr_src, unsigned short* __restrict__ gn) {
    __shared__ __align__(16) float shP[4][64 * 12];   // 12 KB
    __shared__ int shS[4][64];                        // 1 KB
    int wslot = threadIdx.x >> 6;
    int wv = blockIdx.x * 4 + wslot;                  // 10000 waves
    int lane = threadIdx.x & 63;
    int k = lane & 31, half = lane >> 5;
    float* P = shP[wslot];
    int*   S = shS[wslot];
#pragma unroll
    for (int rep = 0; rep < 2; rep++) {
        int n = wv + rep * 10000;
        int beg = row_start[n], deg = row_start[n + 1] - beg;
        const float* sdp = s_dst + (size_t)n * HEADS;
        float sd[10];
#pragma unroll
        for (int q = 0; q < 5; q++) {
            float2 v = *(const float2*)(sdp + 2 * q);
            sd[2 * q] = v.x; sd[2 * q + 1] = v.y;
        }
        float g[10], la[10];
#pragma unroll
        for (int h = 0; h < 10; h++) { g[h] = 0.f; la[h] = 0.f; }

        for (int c0 = 0; c0 < deg; c0 += 64) {
            int dc = min(deg - c0, 64);
            bool act = lane < dc;
            int s_e = csr_src[beg + c0 + min(lane, dc - 1)];
            const float* ssp = s_src + (size_t)s_e * HEADS;
            float p[10];
#pragma unroll
            for (int q = 0; q < 5; q++) {
                float2 v = *(const float2*)(ssp + 2 * q);
                float e0 = v.x + sd[2 * q];
                float e1 = v.y + sd[2 * q + 1];
                e0 = (e0 >= 0.f) ? e0 : 0.2f * e0;
                e1 = (e1 >= 0.f) ? e1 : 0.2f * e1;
                p[2 * q]     = act ? __expf(e0) : 0.f;
                p[2 * q + 1] = act ? __expf(e1) : 0.f;
            }
            // stage this chunk's (s, p) in LDS — pad rows carry p = 0
            S[lane] = s_e;
            *(float4*)&P[lane * 12 + 0] = (float4){p[0], p[1], p[2], p[3]};
            *(float4*)&P[lane * 12 + 4] = (float4){p[4], p[5], p[6], p[7]};
            *(float2*)&P[lane * 12 + 8] = (float2){p[8], p[9]};
            asm volatile("s_waitcnt lgkmcnt(0)" ::: "memory");

            for (int i = 0; i < dc; i += 2) {
                int e = i + half;                  // <= 63 always
                int s = S[e];
                float4 pA = *(const float4*)&P[e * 12 + 0];
                float4 pB = *(const float4*)&P[e * 12 + 4];
                float2 pC = *(const float2*)&P[e * 12 + 8];
                float v = (float)feats16[(size_t)s * F_IN + k];
                g[0] += pA.x * v; g[1] += pA.y * v; g[2] += pA.z * v; g[3] += pA.w * v;
                g[4] += pB.x * v; g[5] += pB.y * v; g[6] += pB.z * v; g[7] += pB.w * v;
                g[8] += pC.x * v; g[9] += pC.y * v;
                la[0] += pA.x; la[1] += pA.y; la[2] += pA.z; la[3] += pA.w;
                la[4] += pB.x; la[5] += pB.y; la[6] += pB.z; la[7] += pB.w;
                la[8] += pC.x; la[9] += pC.y;
            }
            asm volatile("s_waitcnt lgkmcnt(0)" ::: "memory");  // reads done before next chunk's writes
        }
#pragma unroll
        for (int h = 0; h < 10; h++) {
            g[h]  += __shfl_xor(g[h], 32);
            la[h] += __shfl_xor(la[h], 32);
        }
        if (half == 0) {
            unsigned short* gp = gn + (size_t)n * C1 + k;
#pragma unroll
            for (int h = 0; h < 10; h++)
                gp[h * 32] = f2bf(g[h] / fmaxf(la[h], 1e-16f));
        }
    }
}

// ---------------------------------------------------------------------------
// h1 = ELU(gn @ W1 (per-head 32x32) + b1), bf16 out. MFMA 16x16x32.
// ---------------------------------------------------------------------------
__global__ __launch_bounds__(256) void h1_mfma_kernel(
        const unsigned short* __restrict__ gn, const unsigned short* __restrict__ W1p,
        const float* __restrict__ b1, unsigned short* __restrict__ h1b) {
    int unit = blockIdx.x * 4 + (threadIdx.x >> 6);
    if (unit >= 1250 * HEADS) return;
    int lane = threadIdx.x & 63;
    int tile = unit / HEADS;
    int h = unit - tile * HEADS;
    int quad = lane >> 4, col = lane & 15;
    int row0 = tile * 16;

    bf16x8 a = *(const bf16x8*)(gn + (size_t)(row0 + col) * C1 + h * 32 + quad * 8);
    bf16x8 bA = ((const bf16x8*)W1p)[(h * 2 + 0) * 64 + lane];
    bf16x8 bB = ((const bf16x8*)W1p)[(h * 2 + 1) * 64 + lane];
    floatx4 z = {0.f, 0.f, 0.f, 0.f};
    floatx4 c0 = __builtin_amdgcn_mfma_f32_16x16x32_bf16(a, bA, z, 0, 0, 0);
    floatx4 c1 = __builtin_amdgcn_mfma_f32_16x16x32_bf16(a, bB, z, 0, 0, 0);

    float bias0 = b1[h * 32 + col];
    float bias1 = b1[h * 32 + 16 + col];
#pragma unroll
    for (int reg = 0; reg < 4; reg++) {
        int row = row0 + quad * 4 + reg;
        float o0 = c0[reg] + bias0;
        float o1 = c1[reg] + bias1;
        o0 = (o0 > 0.f) ? o0 : (__expf(o0) - 1.f);
        o1 = (o1 > 0.f) ? o1 : (__expf(o1) - 1.f);
        h1b[(size_t)row * C1 + h * 32 + col]      = f2bf(o0);
        h1b[(size_t)row * C1 + h * 32 + 16 + col] = f2bf(o1);
    }
}

// ---------------------------------------------------------------------------
// Layer 2 GEMM via MFMA bf16: xw2 (fp16 out) + fused fp32 s2 scores
// ---------------------------------------------------------------------------
__global__ __launch_bounds__(256) void gemm2_mfma_kernel(
        const unsigned short* __restrict__ h1b, const unsigned short* __restrict__ W2p,
        const float* __restrict__ a_src, const float* __restrict__ a_dst,
        f16* __restrict__ xw2h, float* __restrict__ s_src2, float* __restrict__ s_dst2) {
    int wave = threadIdx.x >> 6;
    int lane = threadIdx.x & 63;
    int tile = blockIdx.x * 4 + wave;            // 16-row tile index
    if (tile >= N_NODES / 16) return;            // 1250 tiles (wave-uniform exit)
    int quad = lane >> 4, col = lane & 15;
    int row0 = tile * 16;

    floatx4 acc[8];
#pragma unroll
    for (int ct = 0; ct < 8; ct++) acc[ct] = (floatx4){0.f, 0.f, 0.f, 0.f};

    const bf16x8* pb = (const bf16x8*)W2p;       // [(kb*8+ct)*64 + lane]
    int m = row0 + col;                          // A-frag row for this lane
#pragma unroll
    for (int kb = 0; kb < 10; kb++) {
        bf16x8 a = *(const bf16x8*)(h1b + (size_t)m * C1 + kb * 32 + quad * 8);
#pragma unroll
        for (int ct = 0; ct < 8; ct++) {
            bf16x8 b = pb[(kb * 8 + ct) * 64 + lane];
            acc[ct] = __builtin_amdgcn_mfma_f32_16x16x32_bf16(a, b, acc[ct], 0, 0, 0);
        }
    }

    float asv[8], adv[8];
#pragma unroll
    for (int ct = 0; ct < 8; ct++) { asv[ct] = a_src[ct * 16 + col]; adv[ct] = a_dst[ct * 16 + col]; }

#pragma unroll
    for (int reg = 0; reg < 4; reg++) {
        int row = row0 + quad * 4 + reg;
        float vs = 0.f, vd = 0.f;
#pragma unroll
        for (int ct = 0; ct < 8; ct++) {
            float v = acc[ct][reg];
            xw2h[(size_t)row * C2 + ct * 16 + col] = (f16)v;
            vs += v * asv[ct];
            vd += v * adv[ct];
        }
#pragma unroll
        for (int off = 8; off >= 1; off >>= 1) {
            vs += __shfl_xor(vs, off);
            vd += __shfl_xor(vd, off);
        }
        if (col == 0) { s_src2[row] = vs; s_dst2[row] = vd; }
    }
}

// ---------------------------------------------------------------------------
// Layer 2 aggregation (H=1): wave per node, 2 nodes/wave, no max-subtract.
// Lane owns 2 channels (f16x2 gather). x2 stored fp16.
// ---------------------------------------------------------------------------
__global__ __launch_bounds__(256) void agg2_kernel(
        const f16* __restrict__ xw2h, const float* __restrict__ s_src2,
        const float* __restrict__ s_dst2, const int* __restrict__ row_start,
        const int* __restrict__ csr_src, const float* __restrict__ b2,
        f16* __restrict__ x2h) {
    int wv = blockIdx.x * 4 + (threadIdx.x >> 6);     // 10000 waves
    int lane = threadIdx.x & 63;
#pragma unroll
    for (int rep = 0; rep < 2; rep++) {
        int n = wv + rep * 10000;
        int beg = row_start[n], deg = row_start[n + 1] - beg;
        float sd = s_dst2[n];
        float l = 0.f, a0 = 0.f, a1 = 0.f;

        for (int c0 = 0; c0 < deg; c0 += 64) {
            int dc = min(deg - c0, 64);
            bool act = lane < dc;
            int s_e = csr_src[beg + c0 + min(lane, dc - 1)];
            float e = s_src2[s_e] + sd;
            e = (e >= 0.f) ? e : 0.2f * e;
            float p = act ? __expf(e) : 0.f;
            float su = p;
#pragma unroll
            for (int off = 32; off >= 1; off >>= 1) su += __shfl_xor(su, off);
            l += su;

            int groups = (dc + 7) >> 3;
            for (int g = 0; g < groups; g++) {
                int i0 = g * 8;
                float pp[8]; float2 vv[8];
#pragma unroll
                for (int j = 0; j < 8; j++) {
                    int ii = i0 + j;
                    int idx = min(ii, dc - 1);
                    int s = __shfl(s_e, idx);
                    float ph = __shfl(p, idx);
                    pp[j] = (ii < dc) ? ph : 0.f;
                    f16x2 hv = *(const f16x2*)(xw2h + (size_t)s * C2 + 2 * lane);
                    vv[j].x = (float)hv.x;
                    vv[j].y = (float)hv.y;
                }
#pragma unroll
                for (int j = 0; j < 8; j++) {
                    a0 += pp[j] * vv[j].x;
                    a1 += pp[j] * vv[j].y;
                }
            }
        }

        float linv = 1.f / fmaxf(l, 1e-16f);
        float2 bb = *(const float2*)(b2 + 2 * lane);
        f16x2 o;
        o.x = (f16)fmaxf(a0 * linv + bb.x, 0.f);
        o.y = (f16)fmaxf(a1 * linv + bb.y, 0.f);
        *(f16x2*)(x2h + (size_t)n * C2 + 2 * lane) = o;   // ReLU'd, fp16
    }
}

// ---------------------------------------------------------------------------
// Main output via MFMA f16: out = relu(x2 @ fc_w + fc_b), fp32 stores
// ---------------------------------------------------------------------------
__global__ __launch_bounds__(256) void fc_mfma_kernel(
        const f16* __restrict__ x2h, const f16* __restrict__ FCp,
        const float* __restrict__ fcb, float* __restrict__ out) {
    int wave = threadIdx.x >> 6;
    int lane = threadIdx.x & 63;
    int tile = blockIdx.x * 4 + wave;
    if (tile >= N_NODES / 16) return;
    int quad = lane >> 4, col = lane & 15;
    int row0 = tile * 16;

    floatx4 acc[8];
#pragma unroll
    for (int ct = 0; ct < 8; ct++) acc[ct] = (floatx4){0.f, 0.f, 0.f, 0.f};

    const f16x8* pb = (const f16x8*)FCp;
    int m = row0 + col;
#pragma unroll
    for (int kb = 0; kb < 4; kb++) {
        f16x8 a = *(const f16x8*)(x2h + (size_t)m * C2 + kb * 32 + quad * 8);
#pragma unroll
        for (int ct = 0; ct < 8; ct++) {
            f16x8 b = pb[(kb * 8 + ct) * 64 + lane];
            acc[ct] = __builtin_amdgcn_mfma_f32_16x16x32_f16(a, b, acc[ct], 0, 0, 0);
        }
    }

    float bias[8];
#pragma unroll
    for (int ct = 0; ct < 8; ct++) bias[ct] = fcb[ct * 16 + col];
#pragma unroll
    for (int reg = 0; reg < 4; reg++) {
        int row = row0 + quad * 4 + reg;
#pragma unroll
        for (int ct = 0; ct < 8; ct++)
            out[(size_t)row * C2 + ct * 16 + col] = fmaxf(acc[ct][reg] + bias[ct], 0.f);
    }
}

// ---------------------------------------------------------------------------
// Fused pooling + fc: per-graph max over 200 nodes then relu(mx @ fc_w + fc_b)
// ---------------------------------------------------------------------------
__global__ void pool_fc_kernel(const f16* __restrict__ x2h, const float* __restrict__ fc_w,
                               const float* __restrict__ fc_b, float* __restrict__ outp) {
    __shared__ float mx[C2];
    int g = blockIdx.x, t = threadIdx.x;   // 128
    float m = -1e30f;
    for (int i = 0; i < PER; i++)
        m = fmaxf(m, (float)x2h[(size_t)(g * PER + i) * C2 + t]);
    mx[t] = m;
    __syncthreads();
    float acc = 0.f;
    for (int k = 0; k < C2; k++) acc += mx[k] * fc_w[k * C2 + t];
    outp[g * C2 + t] = fmaxf(acc + fc_b[t], 0.f);
}

// ---------------------------------------------------------------------------
extern "C" void kernel_launch(void* const* d_in, const int* in_sizes, int n_in,
                              void* d_out, int out_size, void* d_ws, size_t ws_size,
                              hipStream_t stream) {
    const float* feats = (const float*)d_in[0];
    const int*   ei    = (const int*)d_in[1];
    const float* W1  = (const float*)d_in[4];
    const float* a1s = (const float*)d_in[5];
    const float* a1d = (const float*)d_in[6];
    const float* b1  = (const float*)d_in[7];
    const float* W2  = (const float*)d_in[8];
    const float* a2s = (const float*)d_in[9];
    const float* a2d = (const float*)d_in[10];
    const float* b2  = (const float*)d_in[11];
    const float* fcw = (const float*)d_in[12];
    const float* fcb = (const float*)d_in[13];

    float* out_main = (float*)d_out;                        // [20000,128]
    float* out_pool = (float*)d_out + (size_t)N_NODES * C2; // [100,128]

    char* p = (char*)d_ws;
    auto alloc = [&](size_t bytes) {
        char* r = p;
        p += (bytes + 255) & ~(size_t)255;
        return r;
    };
    unsigned short* gn   = (unsigned short*)alloc(sizeof(short) * (size_t)N_NODES * C1);
    unsigned short* h1b  = (unsigned short*)alloc(sizeof(short) * (size_t)N_NODES * C1);
    unsigned short* W2p  = (unsigned short*)alloc(sizeof(short) * C1 * C2);
    unsigned short* W1p  = (unsigned short*)alloc(sizeof(short) * HEADS * F_IN * F_IN);
    f16*   FCp     = (f16*)alloc(sizeof(f16) * C2 * C2);
    f16*   feats16 = (f16*)alloc(sizeof(f16) * (size_t)N_NODES * F_IN);
    f16*   xw2h    = (f16*)alloc(sizeof(f16) * (size_t)N_NODES * C2);
    f16*   x2h     = (f16*)alloc(sizeof(f16) * (size_t)N_NODES * C2);
    float* WAs    = (float*)alloc(sizeof(float) * C1);
    float* WAd    = (float*)alloc(sizeof(float) * C1);
    float* s1s    = (float*)alloc(sizeof(float) * N_NODES * HEADS);
    float* s1d    = (float*)alloc(sizeof(float) * N_NODES * HEADS);
    float* s2s    = (float*)alloc(sizeof(float) * N_NODES);
    float* s2d    = (float*)alloc(sizeof(float) * N_NODES);
    int* counts   = (int*)alloc(sizeof(int) * N_NODES * 2);  // counts + cursor
    int* cursor   = counts + N_NODES;
    int* row_start = (int*)alloc(sizeof(int) * (N_NODES + 1));
    int* csr_src  = (int*)alloc(sizeof(int) * ETOT);

    hipMemsetAsync(counts, 0, sizeof(int) * N_NODES * 2, stream);

    prep_kernel<<<HIST_BLOCKS + W2P_BLOCKS + W1P_BLOCKS + FCP_BLOCKS + F16_BLOCKS + 1, 256, 0, stream>>>(
        ei, counts, W2, W2p, W1, W1p, fcw, FCp, a1s, a1d, WAs, WAd, feats, feats16);
    scan_kernel<<<1, 1024, 0, stream>>>(counts, row_start);
    scatter_score_kernel<<<SCAT_BLOCKS + (N_NODES + 63) / 64, 256, 0, stream>>>(
        ei, row_start, cursor, csr_src, feats, WAs, WAd, s1s, s1d);

    aggg1_kernel<<<2500, 256, 0, stream>>>(feats16, s1s, s1d, row_start, csr_src, gn);
    h1_mfma_kernel<<<(1250 * HEADS + 3) / 4, 256, 0, stream>>>(gn, W1p, b1, h1b);
    gemm2_mfma_kernel<<<(N_NODES / 16 + 3) / 4, 256, 0, stream>>>(h1b, W2p, a2s, a2d, xw2h, s2s, s2d);
    agg2_kernel<<<2500, 256, 0, stream>>>(xw2h, s2s, s2d, row_start, csr_src, b2, x2h);
    fc_mfma_kernel<<<(N_NODES / 16 + 3) / 4, 256, 0, stream>>>(x2h, FCp, fcb, out_main);
    pool_fc_kernel<<<NB, C2, 0, stream>>>(x2h, fcw, fcb, out_pool);
}

// Round 10
// 212.221 us; speedup vs baseline: 1.7064x; 1.2023x over previous
//
#include <hip/hip_runtime.h>

// Problem constants (fixed by the reference)
#define N_NODES 20000
#define N_EDGES 320000
#define ETOT    (N_EDGES + N_NODES)   // edges + self-loops = 340000
#define HEADS   10
#define F_IN    32
#define C1      (HEADS * F_IN)        // 320
#define C2      128
#define NB      100
#define PER     200
#define CAP     96                    // CSR bucket capacity (max in-degree << 96)

typedef __attribute__((ext_vector_type(8))) short bf16x8;   // MFMA A/B frag (4 VGPRs)
typedef __attribute__((ext_vector_type(4))) float floatx4;  // MFMA C/D frag
typedef _Float16 f16;
typedef _Float16 f16x2 __attribute__((ext_vector_type(2)));
typedef _Float16 f16x8 __attribute__((ext_vector_type(8)));

static __device__ __forceinline__ unsigned short f2bf(float f) {
    unsigned int u = __float_as_uint(f);
    unsigned int r = (u + 0x7fffu + ((u >> 16) & 1u)) >> 16;   // RNE
    return (unsigned short)r;
}

// ---------------------------------------------------------------------------
// Combined prep: W2/W1/FC MFMA B-frag prep + WA fold + feats->f16 (no hist!)
// ---------------------------------------------------------------------------
#define W2P_BLOCKS  ((C1 * C2 + 255) / 256)             // 160
#define W1P_BLOCKS  ((HEADS * F_IN * F_IN + 255) / 256) // 40
#define FCP_BLOCKS  ((C2 * C2 + 255) / 256)             // 64
#define F16_BLOCKS  ((N_NODES * F_IN / 4 + 255) / 256)  // 625 (x4 vectorized)
__global__ void prep_kernel(const float* __restrict__ W2, unsigned short* __restrict__ W2p,
                            const float* __restrict__ W1, unsigned short* __restrict__ W1p,
                            const float* __restrict__ fcw, f16* __restrict__ FCp,
                            const float* __restrict__ a1s, const float* __restrict__ a1d,
                            float* __restrict__ WAs, float* __restrict__ WAd,
                            const float* __restrict__ feats, f16* __restrict__ feats16) {
    unsigned int b = blockIdx.x;
    if (b < W2P_BLOCKS) {
        int o = b * 256 + threadIdx.x;   // 40960
        if (o >= C1 * C2) return;
        int j    = o & 7;
        int lane = (o >> 3) & 63;
        int ct   = (o >> 9) & 7;
        int kb   = o >> 12;
        int k = kb * 32 + (lane >> 4) * 8 + j;
        int n = ct * 16 + (lane & 15);
        W2p[o] = f2bf(W2[k * C2 + n]);
        return;
    }
    b -= W2P_BLOCKS;
    if (b < W1P_BLOCKS) {
        // B-frag for h1 GEMM: W1p[((h*2+ct)*64+lane)*8+j] = W1[quad*8+j][h*32+ct*16+col]
        int o = b * 256 + threadIdx.x;   // 10240
        if (o >= HEADS * F_IN * F_IN) return;
        int j    = o & 7;
        int lane = (o >> 3) & 63;
        int ct   = (o >> 9) & 1;
        int h    = o >> 10;
        int k = (lane >> 4) * 8 + j;
        int f = ct * 16 + (lane & 15);
        W1p[o] = f2bf(W1[k * C1 + h * 32 + f]);
        return;
    }
    b -= W1P_BLOCKS;
    if (b < FCP_BLOCKS) {
        // B-frag (f16) for fc GEMM, K=128: kb<4, ct<8
        int o = b * 256 + threadIdx.x;   // 16384
        if (o >= C2 * C2) return;
        int j    = o & 7;
        int lane = (o >> 3) & 63;
        int ct   = (o >> 9) & 7;
        int kb   = o >> 12;
        int k = kb * 32 + (lane >> 4) * 8 + j;
        int n = ct * 16 + (lane & 15);
        FCp[o] = (f16)fcw[k * C2 + n];
        return;
    }
    b -= FCP_BLOCKS;
    if (b < F16_BLOCKS) {
        int o = b * 256 + threadIdx.x;
        if (o < N_NODES * F_IN / 4) {
            float4 v = ((const float4*)feats)[o];
            f16* d = feats16 + 4 * o;
            d[0] = (f16)v.x; d[1] = (f16)v.y; d[2] = (f16)v.z; d[3] = (f16)v.w;
        }
        return;
    }
    // one block: fold attention vectors through W1 -> WAs/WAd [32][10]
    int t = threadIdx.x;
    for (int o = t; o < C1; o += 256) {
        int k = o & 31, h = o >> 5;
        float ss = 0.f, dd = 0.f;
#pragma unroll
        for (int f = 0; f < F_IN; f++) {
            float wv = W1[k * C1 + h * 32 + f];
            ss += wv * a1s[h * 32 + f];
            dd += wv * a1d[h * 32 + f];
        }
        WAs[k * HEADS + h] = ss;
        WAd[k * HEADS + h] = dd;
    }
}

// ---------------------------------------------------------------------------
// Fused: bucket-CSR scatter + layer-1 scores (independent work)
//   csr[d*CAP + pos] = s, pos = atomicAdd(cursor[d]);  deg[n] = cursor[n]
//   s_src[n,h] = feats[n,:] . WAs[:,h]   (WAd for s_dst)
// ---------------------------------------------------------------------------
#define SCAT_BLOCKS ((ETOT + 255) / 256)
__global__ __launch_bounds__(256) void scatter_score_kernel(
        const int* __restrict__ ei, int* __restrict__ cursor, int* __restrict__ csr_src,
        const float* __restrict__ feats, const float* __restrict__ WAs,
        const float* __restrict__ WAd, float* __restrict__ s_src,
        float* __restrict__ s_dst) {
    if (blockIdx.x < SCAT_BLOCKS) {
        int e = blockIdx.x * 256 + threadIdx.x;
        if (e >= ETOT) return;
        int s, d;
        if (e < N_EDGES) { s = ei[e]; d = ei[N_EDGES + e]; }
        else             { s = e - N_EDGES; d = s; }
        int pos = atomicAdd(&cursor[d], 1);
        csr_src[(size_t)d * CAP + pos] = s;
        return;
    }
    __shared__ __align__(16) float A[64 * F_IN];   // 8 KB
    __shared__ float Ws[C1], Wd[C1];
    int t = threadIdx.x;
    int n0 = (blockIdx.x - SCAT_BLOCKS) * 64;
    int nrows = min(64, N_NODES - n0);
    if (nrows <= 0) return;
    for (int i = t; i < C1; i += 256) { Ws[i] = WAs[i]; Wd[i] = WAd[i]; }
    const float4* fs = (const float4*)(feats + (size_t)n0 * F_IN);
    float4* Af = (float4*)A;
    for (int i = t; i < nrows * 8; i += 256) Af[i] = fs[i];
    __syncthreads();
    for (int o = t; o < nrows * HEADS; o += 256) {
        int nl = o / HEADS, h = o - nl * HEADS;
        const float* ar = A + nl * F_IN;
        float ss = 0.f, dd = 0.f;
#pragma unroll
        for (int k = 0; k < F_IN; k++) {
            float av = ar[k];
            ss += av * Ws[k * HEADS + h];
            dd += av * Wd[k * HEADS + h];
        }
        s_src[(size_t)(n0 + nl) * HEADS + h] = ss;
        s_dst[(size_t)(n0 + nl) * HEADS + h] = dd;
    }
}

// ---------------------------------------------------------------------------
// Layer-1 gather: gn[n,h,k] = (sum_e p_eh * feats[s_e,k]) / l_h   (bf16 out)
// ONE WAVE per node (2 nodes/wave serial). No block barriers.
// (s, p[0..9]) staged per-chunk in the wave's private LDS region; value loop
// reads with 2-address broadcast b128/b64 (2-way = free). Pad rows carry p=0.
// ---------------------------------------------------------------------------
__global__ __launch_bounds__(256) void aggg1_kernel(
        const f16* __restrict__ feats16, const float* __restrict__ s_src,
        const float* __restrict__ s_dst, const int* __restrict__ deg_arr,
        const int* __restrict__ csr_src, unsigned short* __restrict__ gn) {
    __shared__ __align__(16) float shP[4][64 * 12];   // 12 KB
    __shared__ int shS[4][64];                        // 1 KB
    int wslot = threadIdx.x >> 6;
    int wv = blockIdx.x * 4 + wslot;                  // 10000 waves
    int lane = threadIdx.x & 63;
    int k = lane & 31, half = lane >> 5;
    float* P = shP[wslot];
    int*   S = shS[wslot];
#pragma unroll
    for (int rep = 0; rep < 2; rep++) {
        int n = wv + rep * 10000;
        int beg = n * CAP, deg = deg_arr[n];
        const float* sdp = s_dst + (size_t)n * HEADS;
        float sd[10];
#pragma unroll
        for (int q = 0; q < 5; q++) {
            float2 v = *(const float2*)(sdp + 2 * q);
            sd[2 * q] = v.x; sd[2 * q + 1] = v.y;
        }
        float g[10], la[10];
#pragma unroll
        for (int h = 0; h < 10; h++) { g[h] = 0.f; la[h] = 0.f; }

        for (int c0 = 0; c0 < deg; c0 += 64) {
            int dc = min(deg - c0, 64);
            bool act = lane < dc;
            int s_e = csr_src[beg + c0 + min(lane, dc - 1)];
            const float* ssp = s_src + (size_t)s_e * HEADS;
            float p[10];
#pragma unroll
            for (int q = 0; q < 5; q++) {
                float2 v = *(const float2*)(ssp + 2 * q);
                float e0 = v.x + sd[2 * q];
                float e1 = v.y + sd[2 * q + 1];
                e0 = (e0 >= 0.f) ? e0 : 0.2f * e0;
                e1 = (e1 >= 0.f) ? e1 : 0.2f * e1;
                p[2 * q]     = act ? __expf(e0) : 0.f;
                p[2 * q + 1] = act ? __expf(e1) : 0.f;
            }
            // stage this chunk's (s, p) in LDS — pad rows carry p = 0
            S[lane] = s_e;
            *(float4*)&P[lane * 12 + 0] = (float4){p[0], p[1], p[2], p[3]};
            *(float4*)&P[lane * 12 + 4] = (float4){p[4], p[5], p[6], p[7]};
            *(float2*)&P[lane * 12 + 8] = (float2){p[8], p[9]};
            asm volatile("s_waitcnt lgkmcnt(0)" ::: "memory");

            for (int i = 0; i < dc; i += 2) {
                int e = i + half;                  // <= 63 always
                int s = S[e];
                float4 pA = *(const float4*)&P[e * 12 + 0];
                float4 pB = *(const float4*)&P[e * 12 + 4];
                float2 pC = *(const float2*)&P[e * 12 + 8];
                float v = (float)feats16[(size_t)s * F_IN + k];
                g[0] += pA.x * v; g[1] += pA.y * v; g[2] += pA.z * v; g[3] += pA.w * v;
                g[4] += pB.x * v; g[5] += pB.y * v; g[6] += pB.z * v; g[7] += pB.w * v;
                g[8] += pC.x * v; g[9] += pC.y * v;
                la[0] += pA.x; la[1] += pA.y; la[2] += pA.z; la[3] += pA.w;
                la[4] += pB.x; la[5] += pB.y; la[6] += pB.z; la[7] += pB.w;
                la[8] += pC.x; la[9] += pC.y;
            }
            asm volatile("s_waitcnt lgkmcnt(0)" ::: "memory");  // reads done before next chunk's writes
        }
#pragma unroll
        for (int h = 0; h < 10; h++) {
            g[h]  += __shfl_xor(g[h], 32);
            la[h] += __shfl_xor(la[h], 32);
        }
        if (half == 0) {
            unsigned short* gp = gn + (size_t)n * C1 + k;
#pragma unroll
            for (int h = 0; h < 10; h++)
                gp[h * 32] = f2bf(g[h] / fmaxf(la[h], 1e-16f));
        }
    }
}

// ---------------------------------------------------------------------------
// h1 = ELU(gn @ W1 (per-head 32x32) + b1), bf16 out. MFMA 16x16x32.
// ---------------------------------------------------------------------------
__global__ __launch_bounds__(256) void h1_mfma_kernel(
        const unsigned short* __restrict__ gn, const unsigned short* __restrict__ W1p,
        const float* __restrict__ b1, unsigned short* __restrict__ h1b) {
    int unit = blockIdx.x * 4 + (threadIdx.x >> 6);
    if (unit >= 1250 * HEADS) return;
    int lane = threadIdx.x & 63;
    int tile = unit / HEADS;
    int h = unit - tile * HEADS;
    int quad = lane >> 4, col = lane & 15;
    int row0 = tile * 16;

    bf16x8 a = *(const bf16x8*)(gn + (size_t)(row0 + col) * C1 + h * 32 + quad * 8);
    bf16x8 bA = ((const bf16x8*)W1p)[(h * 2 + 0) * 64 + lane];
    bf16x8 bB = ((const bf16x8*)W1p)[(h * 2 + 1) * 64 + lane];
    floatx4 z = {0.f, 0.f, 0.f, 0.f};
    floatx4 c0 = __builtin_amdgcn_mfma_f32_16x16x32_bf16(a, bA, z, 0, 0, 0);
    floatx4 c1 = __builtin_amdgcn_mfma_f32_16x16x32_bf16(a, bB, z, 0, 0, 0);

    float bias0 = b1[h * 32 + col];
    float bias1 = b1[h * 32 + 16 + col];
#pragma unroll
    for (int reg = 0; reg < 4; reg++) {
        int row = row0 + quad * 4 + reg;
        float o0 = c0[reg] + bias0;
        float o1 = c1[reg] + bias1;
        o0 = (o0 > 0.f) ? o0 : (__expf(o0) - 1.f);
        o1 = (o1 > 0.f) ? o1 : (__expf(o1) - 1.f);
        h1b[(size_t)row * C1 + h * 32 + col]      = f2bf(o0);
        h1b[(size_t)row * C1 + h * 32 + 16 + col] = f2bf(o1);
    }
}

// ---------------------------------------------------------------------------
// Layer 2 GEMM via MFMA bf16: xw2 (fp16 out) + fused fp32 s2 scores
// ---------------------------------------------------------------------------
__global__ __launch_bounds__(256) void gemm2_mfma_kernel(
        const unsigned short* __restrict__ h1b, const unsigned short* __restrict__ W2p,
        const float* __restrict__ a_src, const float* __restrict__ a_dst,
        f16* __restrict__ xw2h, float* __restrict__ s_src2, float* __restrict__ s_dst2) {
    int wave = threadIdx.x >> 6;
    int lane = threadIdx.x & 63;
    int tile = blockIdx.x * 4 + wave;            // 16-row tile index
    if (tile >= N_NODES / 16) return;            // 1250 tiles (wave-uniform exit)
    int quad = lane >> 4, col = lane & 15;
    int row0 = tile * 16;

    floatx4 acc[8];
#pragma unroll
    for (int ct = 0; ct < 8; ct++) acc[ct] = (floatx4){0.f, 0.f, 0.f, 0.f};

    const bf16x8* pb = (const bf16x8*)W2p;       // [(kb*8+ct)*64 + lane]
    int m = row0 + col;                          // A-frag row for this lane
#pragma unroll
    for (int kb = 0; kb < 10; kb++) {
        bf16x8 a = *(const bf16x8*)(h1b + (size_t)m * C1 + kb * 32 + quad * 8);
#pragma unroll
        for (int ct = 0; ct < 8; ct++) {
            bf16x8 b = pb[(kb * 8 + ct) * 64 + lane];
            acc[ct] = __builtin_amdgcn_mfma_f32_16x16x32_bf16(a, b, acc[ct], 0, 0, 0);
        }
    }

    float asv[8], adv[8];
#pragma unroll
    for (int ct = 0; ct < 8; ct++) { asv[ct] = a_src[ct * 16 + col]; adv[ct] = a_dst[ct * 16 + col]; }

#pragma unroll
    for (int reg = 0; reg < 4; reg++) {
        int row = row0 + quad * 4 + reg;
        float vs = 0.f, vd = 0.f;
#pragma unroll
        for (int ct = 0; ct < 8; ct++) {
            float v = acc[ct][reg];
            xw2h[(size_t)row * C2 + ct * 16 + col] = (f16)v;
            vs += v * asv[ct];
            vd += v * adv[ct];
        }
#pragma unroll
        for (int off = 8; off >= 1; off >>= 1) {
            vs += __shfl_xor(vs, off);
            vd += __shfl_xor(vd, off);
        }
        if (col == 0) { s_src2[row] = vs; s_dst2[row] = vd; }
    }
}

// ---------------------------------------------------------------------------
// Layer 2 aggregation (H=1): wave per node, 2 nodes/wave. LDS-staged (s,p),
// branch-free padded value loop (pad rows carry p=0, valid s). x2 fp16 out.
// ---------------------------------------------------------------------------
__global__ __launch_bounds__(256) void agg2_kernel(
        const f16* __restrict__ xw2h, const float* __restrict__ s_src2,
        const float* __restrict__ s_dst2, const int* __restrict__ deg_arr,
        const int* __restrict__ csr_src, const float* __restrict__ b2,
        f16* __restrict__ x2h) {
    __shared__ __align__(8) int2 shE[4][64];          // 2 KB
    int wslot = threadIdx.x >> 6;
    int wv = blockIdx.x * 4 + wslot;                  // 10000 waves
    int lane = threadIdx.x & 63;
    int2* E = shE[wslot];
#pragma unroll
    for (int rep = 0; rep < 2; rep++) {
        int n = wv + rep * 10000;
        int beg = n * CAP, deg = deg_arr[n];
        float sd = s_dst2[n];
        float l = 0.f, a0 = 0.f, a1 = 0.f;

        for (int c0 = 0; c0 < deg; c0 += 64) {
            int dc = min(deg - c0, 64);
            bool act = lane < dc;
            int s_e = csr_src[beg + c0 + min(lane, dc - 1)];
            float e = s_src2[s_e] + sd;
            e = (e >= 0.f) ? e : 0.2f * e;
            float p = act ? __expf(e) : 0.f;
            float su = p;
#pragma unroll
            for (int off = 32; off >= 1; off >>= 1) su += __shfl_xor(su, off);
            l += su;

            E[lane] = make_int2(s_e, __float_as_int(p));
            asm volatile("s_waitcnt lgkmcnt(0)" ::: "memory");

            int dcr = (dc + 3) & ~3;                  // pad rows have p=0
            for (int i = 0; i < dcr; i += 4) {
                int2 e0 = E[i + 0], e1 = E[i + 1], e2 = E[i + 2], e3 = E[i + 3];
                f16x2 v0 = *(const f16x2*)(xw2h + (size_t)e0.x * C2 + 2 * lane);
                f16x2 v1 = *(const f16x2*)(xw2h + (size_t)e1.x * C2 + 2 * lane);
                f16x2 v2 = *(const f16x2*)(xw2h + (size_t)e2.x * C2 + 2 * lane);
                f16x2 v3 = *(const f16x2*)(xw2h + (size_t)e3.x * C2 + 2 * lane);
                float p0 = __int_as_float(e0.y), p1 = __int_as_float(e1.y);
                float p2 = __int_as_float(e2.y), p3 = __int_as_float(e3.y);
                a0 += p0 * (float)v0.x + p1 * (float)v1.x + p2 * (float)v2.x + p3 * (float)v3.x;
                a1 += p0 * (float)v0.y + p1 * (float)v1.y + p2 * (float)v2.y + p3 * (float)v3.y;
            }
            asm volatile("s_waitcnt lgkmcnt(0)" ::: "memory");
        }

        float linv = 1.f / fmaxf(l, 1e-16f);
        float2 bb = *(const float2*)(b2 + 2 * lane);
        f16x2 o;
        o.x = (f16)fmaxf(a0 * linv + bb.x, 0.f);
        o.y = (f16)fmaxf(a1 * linv + bb.y, 0.f);
        *(f16x2*)(x2h + (size_t)n * C2 + 2 * lane) = o;   // ReLU'd, fp16
    }
}

// ---------------------------------------------------------------------------
// Fused main-output MFMA fc + per-graph pooling fc.
//   blocks [0, FCB): out = relu(x2 @ fc_w + fc_b) via f16 MFMA
//   blocks [FCB, FCB+50): 2 graphs/block — max-pool 200 nodes + fc + relu
// ---------------------------------------------------------------------------
#define FCB ((1250 + 3) / 4)   // 313
__global__ __launch_bounds__(256) void fc_pool_kernel(
        const f16* __restrict__ x2h, const f16* __restrict__ FCp,
        const float* __restrict__ fcw, const float* __restrict__ fcb,
        float* __restrict__ out, float* __restrict__ outp) {
    if (blockIdx.x < FCB) {
        int wave = threadIdx.x >> 6;
        int lane = threadIdx.x & 63;
        int tile = blockIdx.x * 4 + wave;
        if (tile >= N_NODES / 16) return;
        int quad = lane >> 4, col = lane & 15;
        int row0 = tile * 16;

        floatx4 acc[8];
#pragma unroll
        for (int ct = 0; ct < 8; ct++) acc[ct] = (floatx4){0.f, 0.f, 0.f, 0.f};

        const f16x8* pb = (const f16x8*)FCp;
        int m = row0 + col;
#pragma unroll
        for (int kb = 0; kb < 4; kb++) {
            f16x8 a = *(const f16x8*)(x2h + (size_t)m * C2 + kb * 32 + quad * 8);
#pragma unroll
            for (int ct = 0; ct < 8; ct++) {
                f16x8 b = pb[(kb * 8 + ct) * 64 + lane];
                acc[ct] = __builtin_amdgcn_mfma_f32_16x16x32_f16(a, b, acc[ct], 0, 0, 0);
            }
        }

        float bias[8];
#pragma unroll
        for (int ct = 0; ct < 8; ct++) bias[ct] = fcb[ct * 16 + col];
#pragma unroll
        for (int reg = 0; reg < 4; reg++) {
            int row = row0 + quad * 4 + reg;
#pragma unroll
            for (int ct = 0; ct < 8; ct++)
                out[(size_t)row * C2 + ct * 16 + col] = fmaxf(acc[ct][reg] + bias[ct], 0.f);
        }
        return;
    }
    // pooling: 2 graphs per block (threads 0..127 -> g0, 128..255 -> g1)
    __shared__ float mx[2][C2];
    int half = threadIdx.x >> 7;
    int t = threadIdx.x & 127;
    int g = (blockIdx.x - FCB) * 2 + half;
    float m = -1e30f;
    for (int i = 0; i < PER; i++)
        m = fmaxf(m, (float)x2h[(size_t)(g * PER + i) * C2 + t]);
    mx[half][t] = m;
    __syncthreads();
    float acc = 0.f;
    for (int k = 0; k < C2; k++) acc += mx[half][k] * fcw[k * C2 + t];
    outp[g * C2 + t] = fmaxf(acc + fcb[t], 0.f);
}

// ---------------------------------------------------------------------------
extern "C" void kernel_launch(void* const* d_in, const int* in_sizes, int n_in,
                              void* d_out, int out_size, void* d_ws, size_t ws_size,
                              hipStream_t stream) {
    const float* feats = (const float*)d_in[0];
    const int*   ei    = (const int*)d_in[1];
    const float* W1  = (const float*)d_in[4];
    const float* a1s = (const float*)d_in[5];
    const float* a1d = (const float*)d_in[6];
    const float* b1  = (const float*)d_in[7];
    const float* W2  = (const float*)d_in[8];
    const float* a2s = (const float*)d_in[9];
    const float* a2d = (const float*)d_in[10];
    const float* b2  = (const float*)d_in[11];
    const float* fcw = (const float*)d_in[12];
    const float* fcb = (const float*)d_in[13];

    float* out_main = (float*)d_out;                        // [20000,128]
    float* out_pool = (float*)d_out + (size_t)N_NODES * C2; // [100,128]

    char* p = (char*)d_ws;
    auto alloc = [&](size_t bytes) {
        char* r = p;
        p += (bytes + 255) & ~(size_t)255;
        return r;
    };
    unsigned short* gn   = (unsigned short*)alloc(sizeof(short) * (size_t)N_NODES * C1);
    unsigned short* h1b  = (unsigned short*)alloc(sizeof(short) * (size_t)N_NODES * C1);
    unsigned short* W2p  = (unsigned short*)alloc(sizeof(short) * C1 * C2);
    unsigned short* W1p  = (unsigned short*)alloc(sizeof(short) * HEADS * F_IN * F_IN);
    f16*   FCp     = (f16*)alloc(sizeof(f16) * C2 * C2);
    f16*   feats16 = (f16*)alloc(sizeof(f16) * (size_t)N_NODES * F_IN);
    f16*   xw2h    = (f16*)alloc(sizeof(f16) * (size_t)N_NODES * C2);
    f16*   x2h     = (f16*)alloc(sizeof(f16) * (size_t)N_NODES * C2);
    float* WAs    = (float*)alloc(sizeof(float) * C1);
    float* WAd    = (float*)alloc(sizeof(float) * C1);
    float* s1s    = (float*)alloc(sizeof(float) * N_NODES * HEADS);
    float* s1d    = (float*)alloc(sizeof(float) * N_NODES * HEADS);
    float* s2s    = (float*)alloc(sizeof(float) * N_NODES);
    float* s2d    = (float*)alloc(sizeof(float) * N_NODES);
    int* cursor   = (int*)alloc(sizeof(int) * N_NODES);       // per-dst fill count
    int* csr_src  = (int*)alloc(sizeof(int) * N_NODES * CAP); // bucket CSR

    hipMemsetAsync(cursor, 0, sizeof(int) * N_NODES, stream);

    prep_kernel<<<W2P_BLOCKS + W1P_BLOCKS + FCP_BLOCKS + F16_BLOCKS + 1, 256, 0, stream>>>(
        W2, W2p, W1, W1p, fcw, FCp, a1s, a1d, WAs, WAd, feats, feats16);
    scatter_score_kernel<<<SCAT_BLOCKS + (N_NODES + 63) / 64, 256, 0, stream>>>(
        ei, cursor, csr_src, feats, WAs, WAd, s1s, s1d);

    aggg1_kernel<<<2500, 256, 0, stream>>>(feats16, s1s, s1d, cursor, csr_src, gn);
    h1_mfma_kernel<<<(1250 * HEADS + 3) / 4, 256, 0, stream>>>(gn, W1p, b1, h1b);
    gemm2_mfma_kernel<<<(N_NODES / 16 + 3) / 4, 256, 0, stream>>>(h1b, W2p, a2s, a2d, xw2h, s2s, s2d);
    agg2_kernel<<<2500, 256, 0, stream>>>(xw2h, s2s, s2d, cursor, csr_src, b2, x2h);
    fc_pool_kernel<<<FCB + NB / 2, 256, 0, stream>>>(x2h, FCp, fcw, fcb, out_main, out_pool);
}

// Round 11
// 200.324 us; speedup vs baseline: 1.8078x; 1.0594x over previous
//
#include <hip/hip_runtime.h>

// Problem constants (fixed by the reference)
#define N_NODES 20000
#define N_EDGES 320000
#define ETOT    (N_EDGES + N_NODES)   // edges + self-loops = 340000
#define HEADS   10
#define F_IN    32
#define C1      (HEADS * F_IN)        // 320
#define C2      128
#define NB      100
#define PER     200
#define CAP     96                    // CSR bucket capacity (max in-degree << 96)
#define HSTRIDE 328                   // padded h1-tile row stride (ushort)

typedef __attribute__((ext_vector_type(8))) short bf16x8;   // MFMA A/B frag (4 VGPRs)
typedef __attribute__((ext_vector_type(4))) float floatx4;  // MFMA C/D frag
typedef _Float16 f16;
typedef _Float16 f16x2 __attribute__((ext_vector_type(2)));
typedef _Float16 f16x8 __attribute__((ext_vector_type(8)));

static __device__ __forceinline__ unsigned short f2bf(float f) {
    unsigned int u = __float_as_uint(f);
    unsigned int r = (u + 0x7fffu + ((u >> 16) & 1u)) >> 16;   // RNE
    return (unsigned short)r;
}

// ---------------------------------------------------------------------------
// Combined prep: cursor zero + W2/W1/FC MFMA B-frag prep + WA fold + feats->f16
// ---------------------------------------------------------------------------
#define CURZ_BLOCKS ((N_NODES + 255) / 256)             // 79
#define W2P_BLOCKS  ((C1 * C2 + 255) / 256)             // 160
#define W1P_BLOCKS  ((HEADS * F_IN * F_IN + 255) / 256) // 40
#define FCP_BLOCKS  ((C2 * C2 + 255) / 256)             // 64
#define F16_BLOCKS  ((N_NODES * F_IN / 4 + 255) / 256)  // 625 (x4 vectorized)
__global__ void prep_kernel(int* __restrict__ cursor,
                            const float* __restrict__ W2, unsigned short* __restrict__ W2p,
                            const float* __restrict__ W1, unsigned short* __restrict__ W1p,
                            const float* __restrict__ fcw, f16* __restrict__ FCp,
                            const float* __restrict__ a1s, const float* __restrict__ a1d,
                            float* __restrict__ WAs, float* __restrict__ WAd,
                            const float* __restrict__ feats, f16* __restrict__ feats16) {
    unsigned int b = blockIdx.x;
    if (b < CURZ_BLOCKS) {
        int o = b * 256 + threadIdx.x;
        if (o < N_NODES) cursor[o] = 0;
        return;
    }
    b -= CURZ_BLOCKS;
    if (b < W2P_BLOCKS) {
        int o = b * 256 + threadIdx.x;   // 40960
        if (o >= C1 * C2) return;
        int j    = o & 7;
        int lane = (o >> 3) & 63;
        int ct   = (o >> 9) & 7;
        int kb   = o >> 12;
        int k = kb * 32 + (lane >> 4) * 8 + j;
        int n = ct * 16 + (lane & 15);
        W2p[o] = f2bf(W2[k * C2 + n]);
        return;
    }
    b -= W2P_BLOCKS;
    if (b < W1P_BLOCKS) {
        // B-frag for h1 GEMM: W1p[((h*2+ct)*64+lane)*8+j] = W1[quad*8+j][h*32+ct*16+col]
        int o = b * 256 + threadIdx.x;   // 10240
        if (o >= HEADS * F_IN * F_IN) return;
        int j    = o & 7;
        int lane = (o >> 3) & 63;
        int ct   = (o >> 9) & 1;
        int h    = o >> 10;
        int k = (lane >> 4) * 8 + j;
        int f = ct * 16 + (lane & 15);
        W1p[o] = f2bf(W1[k * C1 + h * 32 + f]);
        return;
    }
    b -= W1P_BLOCKS;
    if (b < FCP_BLOCKS) {
        // B-frag (f16) for fc GEMM, K=128: kb<4, ct<8
        int o = b * 256 + threadIdx.x;   // 16384
        if (o >= C2 * C2) return;
        int j    = o & 7;
        int lane = (o >> 3) & 63;
        int ct   = (o >> 9) & 7;
        int kb   = o >> 12;
        int k = kb * 32 + (lane >> 4) * 8 + j;
        int n = ct * 16 + (lane & 15);
        FCp[o] = (f16)fcw[k * C2 + n];
        return;
    }
    b -= FCP_BLOCKS;
    if (b < F16_BLOCKS) {
        int o = b * 256 + threadIdx.x;
        if (o < N_NODES * F_IN / 4) {
            float4 v = ((const float4*)feats)[o];
            f16* d = feats16 + 4 * o;
            d[0] = (f16)v.x; d[1] = (f16)v.y; d[2] = (f16)v.z; d[3] = (f16)v.w;
        }
        return;
    }
    // one block: fold attention vectors through W1 -> WAs/WAd [32][10]
    int t = threadIdx.x;
    for (int o = t; o < C1; o += 256) {
        int k = o & 31, h = o >> 5;
        float ss = 0.f, dd = 0.f;
#pragma unroll
        for (int f = 0; f < F_IN; f++) {
            float wv = W1[k * C1 + h * 32 + f];
            ss += wv * a1s[h * 32 + f];
            dd += wv * a1d[h * 32 + f];
        }
        WAs[k * HEADS + h] = ss;
        WAd[k * HEADS + h] = dd;
    }
}

// ---------------------------------------------------------------------------
// Fused: bucket-CSR scatter + layer-1 scores (independent work)
// ---------------------------------------------------------------------------
#define SCAT_BLOCKS ((ETOT + 255) / 256)
__global__ __launch_bounds__(256) void scatter_score_kernel(
        const int* __restrict__ ei, int* __restrict__ cursor, int* __restrict__ csr_src,
        const float* __restrict__ feats, const float* __restrict__ WAs,
        const float* __restrict__ WAd, float* __restrict__ s_src,
        float* __restrict__ s_dst) {
    if (blockIdx.x < SCAT_BLOCKS) {
        int e = blockIdx.x * 256 + threadIdx.x;
        if (e >= ETOT) return;
        int s, d;
        if (e < N_EDGES) { s = ei[e]; d = ei[N_EDGES + e]; }
        else             { s = e - N_EDGES; d = s; }
        int pos = atomicAdd(&cursor[d], 1);
        csr_src[(size_t)d * CAP + pos] = s;
        return;
    }
    __shared__ __align__(16) float A[64 * F_IN];   // 8 KB
    __shared__ float Ws[C1], Wd[C1];
    int t = threadIdx.x;
    int n0 = (blockIdx.x - SCAT_BLOCKS) * 64;
    int nrows = min(64, N_NODES - n0);
    if (nrows <= 0) return;
    for (int i = t; i < C1; i += 256) { Ws[i] = WAs[i]; Wd[i] = WAd[i]; }
    const float4* fs = (const float4*)(feats + (size_t)n0 * F_IN);
    float4* Af = (float4*)A;
    for (int i = t; i < nrows * 8; i += 256) Af[i] = fs[i];
    __syncthreads();
    for (int o = t; o < nrows * HEADS; o += 256) {
        int nl = o / HEADS, h = o - nl * HEADS;
        const float* ar = A + nl * F_IN;
        float ss = 0.f, dd = 0.f;
#pragma unroll
        for (int k = 0; k < F_IN; k++) {
            float av = ar[k];
            ss += av * Ws[k * HEADS + h];
            dd += av * Wd[k * HEADS + h];
        }
        s_src[(size_t)(n0 + nl) * HEADS + h] = ss;
        s_dst[(size_t)(n0 + nl) * HEADS + h] = dd;
    }
}

// ---------------------------------------------------------------------------
// Layer-1 gather: gn[n,h,k] = (sum_e p_eh * feats[s_e,k]) / l_h   (bf16 out)
// ONE WAVE per node (2 nodes/wave serial), no block barriers.
// Weights staged TRANSPOSED as f16 (P[h][e], p <= ~e^6 << f16 max); value
// loop: 4 edges/step, each half owns an edge-pair — one ds_read_b32 per head
// gives a p-pair, fdot2 accumulates value and l sums in fp32.
// ---------------------------------------------------------------------------
__global__ __launch_bounds__(256) void aggg1_kernel(
        const f16* __restrict__ feats16, const float* __restrict__ s_src,
        const float* __restrict__ s_dst, const int* __restrict__ deg_arr,
        const int* __restrict__ csr_src, unsigned short* __restrict__ gn) {
    __shared__ __align__(4) f16 shP[4][HEADS * 64];   // 1.25 KB / slot
    __shared__ __align__(8) int shS[4][64];
    int wslot = threadIdx.x >> 6;
    int wv = blockIdx.x * 4 + wslot;                  // 10000 waves
    int lane = threadIdx.x & 63;
    int k = lane & 31, half = lane >> 5;
    f16* P = shP[wslot];
    int* S = shS[wslot];
    const f16x2 ones = {(f16)1.f, (f16)1.f};
#pragma unroll
    for (int rep = 0; rep < 2; rep++) {
        int n = wv + rep * 10000;
        int beg = n * CAP, deg = deg_arr[n];
        const float* sdp = s_dst + (size_t)n * HEADS;
        float sd[10];
#pragma unroll
        for (int q = 0; q < 5; q++) {
            float2 v = *(const float2*)(sdp + 2 * q);
            sd[2 * q] = v.x; sd[2 * q + 1] = v.y;
        }
        float g[10], la[10];
#pragma unroll
        for (int h = 0; h < 10; h++) { g[h] = 0.f; la[h] = 0.f; }

        for (int c0 = 0; c0 < deg; c0 += 64) {
            int dc = min(deg - c0, 64);
            bool act = lane < dc;
            int s_e = csr_src[beg + c0 + min(lane, dc - 1)];
            const float* ssp = s_src + (size_t)s_e * HEADS;
            float p[10];
#pragma unroll
            for (int q = 0; q < 5; q++) {
                float2 v = *(const float2*)(ssp + 2 * q);
                float e0 = v.x + sd[2 * q];
                float e1 = v.y + sd[2 * q + 1];
                e0 = (e0 >= 0.f) ? e0 : 0.2f * e0;   // leaky_relu(0.2)
                e1 = (e1 >= 0.f) ? e1 : 0.2f * e1;
                p[2 * q]     = act ? __expf(e0) : 0.f;
                p[2 * q + 1] = act ? __expf(e1) : 0.f;
            }
            // stage transposed f16 weights; pad edges carry p = 0
            S[lane] = s_e;
#pragma unroll
            for (int h = 0; h < 10; h++) P[h * 64 + lane] = (f16)p[h];
            asm volatile("s_waitcnt lgkmcnt(0)" ::: "memory");

            int dcp = (dc + 3) & ~3;
            for (int i = 0; i < dcp; i += 4) {
                int e0 = i + half * 2;               // this half's edge pair
                int2 ss2 = *(const int2*)&S[e0];
                f16x2 v;
                v.x = feats16[(size_t)ss2.x * F_IN + k];
                v.y = feats16[(size_t)ss2.y * F_IN + k];
#pragma unroll
                for (int h = 0; h < 10; h++) {
                    f16x2 pp = *(const f16x2*)&P[h * 64 + e0];
                    g[h]  = __builtin_amdgcn_fdot2(pp, v, g[h], false);
                    la[h] = __builtin_amdgcn_fdot2(pp, ones, la[h], false);
                }
            }
            asm volatile("s_waitcnt lgkmcnt(0)" ::: "memory");  // reads done before next chunk
        }
#pragma unroll
        for (int h = 0; h < 10; h++) {
            g[h]  += __shfl_xor(g[h], 32);
            la[h] += __shfl_xor(la[h], 32);
        }
        if (half == 0) {
            unsigned short* gp = gn + (size_t)n * C1 + k;
#pragma unroll
            for (int h = 0; h < 10; h++)
                gp[h * 32] = f2bf(g[h] / fmaxf(la[h], 1e-16f));
        }
    }
}

// ---------------------------------------------------------------------------
// Fused h1 + gemm2: per 16-row tile (2 waves/tile):
//   phase 1: h1 = ELU(gn @ W1 + b1) per head (wave w: heads 5w..5w+4),
//            staged bf16 in padded LDS tile [16][HSTRIDE]
//   phase 2: xw2 = h1 @ W2 (f16 out) + fused s2 scores (split cols, LDS-reduced)
// ---------------------------------------------------------------------------
__global__ __launch_bounds__(256) void h1gemm2_kernel(
        const unsigned short* __restrict__ gn, const unsigned short* __restrict__ W1p,
        const float* __restrict__ b1, const unsigned short* __restrict__ W2p,
        const float* __restrict__ a_src, const float* __restrict__ a_dst,
        f16* __restrict__ xw2h, float* __restrict__ s_src2, float* __restrict__ s_dst2) {
    __shared__ unsigned short H[2][16 * HSTRIDE];   // 21 KB
    __shared__ float redS[2][2][16], redD[2][2][16];
    int waveId = threadIdx.x >> 6;
    int tl = waveId >> 1;                // tile slot in block
    int w  = waveId & 1;                 // wave within tile
    int tile = blockIdx.x * 2 + tl;      // 625 blocks x 2 = 1250 tiles exactly
    int lane = threadIdx.x & 63;
    int quad = lane >> 4, col = lane & 15;
    int row0 = tile * 16;

    // ---- phase 1: h1 for heads 5w..5w+4 ----
#pragma unroll
    for (int hh = 0; hh < 5; hh++) {
        int h = w * 5 + hh;
        bf16x8 a = *(const bf16x8*)(gn + (size_t)(row0 + col) * C1 + h * 32 + quad * 8);
        bf16x8 bA = ((const bf16x8*)W1p)[(h * 2 + 0) * 64 + lane];
        bf16x8 bB = ((const bf16x8*)W1p)[(h * 2 + 1) * 64 + lane];
        floatx4 z = {0.f, 0.f, 0.f, 0.f};
        floatx4 c0 = __builtin_amdgcn_mfma_f32_16x16x32_bf16(a, bA, z, 0, 0, 0);
        floatx4 c1 = __builtin_amdgcn_mfma_f32_16x16x32_bf16(a, bB, z, 0, 0, 0);
        float bias0 = b1[h * 32 + col];
        float bias1 = b1[h * 32 + 16 + col];
#pragma unroll
        for (int reg = 0; reg < 4; reg++) {
            int r = quad * 4 + reg;
            float o0 = c0[reg] + bias0;
            float o1 = c1[reg] + bias1;
            o0 = (o0 > 0.f) ? o0 : (__expf(o0) - 1.f);
            o1 = (o1 > 0.f) ? o1 : (__expf(o1) - 1.f);
            H[tl][r * HSTRIDE + h * 32 + col]      = f2bf(o0);
            H[tl][r * HSTRIDE + h * 32 + 16 + col] = f2bf(o1);
        }
    }
    __syncthreads();

    // ---- phase 2: gemm2, wave w covers cols 64w..64w+63 (ct = 4w..4w+3) ----
    floatx4 acc[4];
#pragma unroll
    for (int c = 0; c < 4; c++) acc[c] = (floatx4){0.f, 0.f, 0.f, 0.f};
    const bf16x8* pb = (const bf16x8*)W2p;
#pragma unroll
    for (int kb = 0; kb < 10; kb++) {
        bf16x8 a = *(const bf16x8*)&H[tl][(lane & 15) * HSTRIDE + kb * 32 + quad * 8];
#pragma unroll
        for (int c = 0; c < 4; c++) {
            bf16x8 b = pb[(kb * 8 + (4 * w + c)) * 64 + lane];
            acc[c] = __builtin_amdgcn_mfma_f32_16x16x32_bf16(a, b, acc[c], 0, 0, 0);
        }
    }
    float asv[4], adv[4];
#pragma unroll
    for (int c = 0; c < 4; c++) {
        asv[c] = a_src[(4 * w + c) * 16 + col];
        adv[c] = a_dst[(4 * w + c) * 16 + col];
    }
#pragma unroll
    for (int reg = 0; reg < 4; reg++) {
        int row = row0 + quad * 4 + reg;
        float vs = 0.f, vd = 0.f;
#pragma unroll
        for (int c = 0; c < 4; c++) {
            float v = acc[c][reg];
            xw2h[(size_t)row * C2 + (4 * w + c) * 16 + col] = (f16)v;
            vs += v * asv[c];
            vd += v * adv[c];
        }
#pragma unroll
        for (int off = 8; off >= 1; off >>= 1) {
            vs += __shfl_xor(vs, off);
            vd += __shfl_xor(vd, off);
        }
        if (col == 0) { redS[tl][w][quad * 4 + reg] = vs; redD[tl][w][quad * 4 + reg] = vd; }
    }
    __syncthreads();
    if (w == 0) {
        if (lane < 16)
            s_src2[row0 + lane] = redS[tl][0][lane] + redS[tl][1][lane];
        else if (lane < 32)
            s_dst2[row0 + lane - 16] = redD[tl][0][lane - 16] + redD[tl][1][lane - 16];
    }
}

// ---------------------------------------------------------------------------
// Layer 2 aggregation (H=1): wave per node, 2 nodes/wave. LDS-staged (s,p),
// branch-free padded value loop (pad rows carry p=0, valid s). x2 fp16 out.
// ---------------------------------------------------------------------------
__global__ __launch_bounds__(256) void agg2_kernel(
        const f16* __restrict__ xw2h, const float* __restrict__ s_src2,
        const float* __restrict__ s_dst2, const int* __restrict__ deg_arr,
        const int* __restrict__ csr_src, const float* __restrict__ b2,
        f16* __restrict__ x2h) {
    __shared__ __align__(8) int2 shE[4][64];          // 2 KB
    int wslot = threadIdx.x >> 6;
    int wv = blockIdx.x * 4 + wslot;                  // 10000 waves
    int lane = threadIdx.x & 63;
    int2* E = shE[wslot];
#pragma unroll
    for (int rep = 0; rep < 2; rep++) {
        int n = wv + rep * 10000;
        int beg = n * CAP, deg = deg_arr[n];
        float sd = s_dst2[n];
        float l = 0.f, a0 = 0.f, a1 = 0.f;

        for (int c0 = 0; c0 < deg; c0 += 64) {
            int dc = min(deg - c0, 64);
            bool act = lane < dc;
            int s_e = csr_src[beg + c0 + min(lane, dc - 1)];
            float e = s_src2[s_e] + sd;
            e = (e >= 0.f) ? e : 0.2f * e;
            float p = act ? __expf(e) : 0.f;
            float su = p;
#pragma unroll
            for (int off = 32; off >= 1; off >>= 1) su += __shfl_xor(su, off);
            l += su;

            E[lane] = make_int2(s_e, __float_as_int(p));
            asm volatile("s_waitcnt lgkmcnt(0)" ::: "memory");

            int dcr = (dc + 3) & ~3;                  // pad rows have p=0
            for (int i = 0; i < dcr; i += 4) {
                int2 e0 = E[i + 0], e1 = E[i + 1], e2 = E[i + 2], e3 = E[i + 3];
                f16x2 v0 = *(const f16x2*)(xw2h + (size_t)e0.x * C2 + 2 * lane);
                f16x2 v1 = *(const f16x2*)(xw2h + (size_t)e1.x * C2 + 2 * lane);
                f16x2 v2 = *(const f16x2*)(xw2h + (size_t)e2.x * C2 + 2 * lane);
                f16x2 v3 = *(const f16x2*)(xw2h + (size_t)e3.x * C2 + 2 * lane);
                float p0 = __int_as_float(e0.y), p1 = __int_as_float(e1.y);
                float p2 = __int_as_float(e2.y), p3 = __int_as_float(e3.y);
                a0 += p0 * (float)v0.x + p1 * (float)v1.x + p2 * (float)v2.x + p3 * (float)v3.x;
                a1 += p0 * (float)v0.y + p1 * (float)v1.y + p2 * (float)v2.y + p3 * (float)v3.y;
            }
            asm volatile("s_waitcnt lgkmcnt(0)" ::: "memory");
        }

        float linv = 1.f / fmaxf(l, 1e-16f);
        float2 bb = *(const float2*)(b2 + 2 * lane);
        f16x2 o;
        o.x = (f16)fmaxf(a0 * linv + bb.x, 0.f);
        o.y = (f16)fmaxf(a1 * linv + bb.y, 0.f);
        *(f16x2*)(x2h + (size_t)n * C2 + 2 * lane) = o;   // ReLU'd, fp16
    }
}

// ---------------------------------------------------------------------------
// Fused main-output MFMA fc + per-graph pooling fc.
// ---------------------------------------------------------------------------
#define FCB ((1250 + 3) / 4)   // 313
__global__ __launch_bounds__(256) void fc_pool_kernel(
        const f16* __restrict__ x2h, const f16* __restrict__ FCp,
        const float* __restrict__ fcw, const float* __restrict__ fcb,
        float* __restrict__ out, float* __restrict__ outp) {
    if (blockIdx.x < FCB) {
        int wave = threadIdx.x >> 6;
        int lane = threadIdx.x & 63;
        int tile = blockIdx.x * 4 + wave;
        if (tile >= N_NODES / 16) return;
        int quad = lane >> 4, col = lane & 15;
        int row0 = tile * 16;

        floatx4 acc[8];
#pragma unroll
        for (int ct = 0; ct < 8; ct++) acc[ct] = (floatx4){0.f, 0.f, 0.f, 0.f};

        const f16x8* pb = (const f16x8*)FCp;
        int m = row0 + col;
#pragma unroll
        for (int kb = 0; kb < 4; kb++) {
            f16x8 a = *(const f16x8*)(x2h + (size_t)m * C2 + kb * 32 + quad * 8);
#pragma unroll
            for (int ct = 0; ct < 8; ct++) {
                f16x8 b = pb[(kb * 8 + ct) * 64 + lane];
                acc[ct] = __builtin_amdgcn_mfma_f32_16x16x32_f16(a, b, acc[ct], 0, 0, 0);
            }
        }

        float bias[8];
#pragma unroll
        for (int ct = 0; ct < 8; ct++) bias[ct] = fcb[ct * 16 + col];
#pragma unroll
        for (int reg = 0; reg < 4; reg++) {
            int row = row0 + quad * 4 + reg;
#pragma unroll
            for (int ct = 0; ct < 8; ct++)
                out[(size_t)row * C2 + ct * 16 + col] = fmaxf(acc[ct][reg] + bias[ct], 0.f);
        }
        return;
    }
    // pooling: 2 graphs per block (threads 0..127 -> g0, 128..255 -> g1)
    __shared__ float mx[2][C2];
    int half = threadIdx.x >> 7;
    int t = threadIdx.x & 127;
    int g = (blockIdx.x - FCB) * 2 + half;
    float m = -1e30f;
    for (int i = 0; i < PER; i++)
        m = fmaxf(m, (float)x2h[(size_t)(g * PER + i) * C2 + t]);
    mx[half][t] = m;
    __syncthreads();
    float acc = 0.f;
    for (int k = 0; k < C2; k++) acc += mx[half][k] * fcw[k * C2 + t];
    outp[g * C2 + t] = fmaxf(acc + fcb[t], 0.f);
}

// ---------------------------------------------------------------------------
extern "C" void kernel_launch(void* const* d_in, const int* in_sizes, int n_in,
                              void* d_out, int out_size, void* d_ws, size_t ws_size,
                              hipStream_t stream) {
    const float* feats = (const float*)d_in[0];
    const int*   ei    = (const int*)d_in[1];
    const float* W1  = (const float*)d_in[4];
    const float* a1s = (const float*)d_in[5];
    const float* a1d = (const float*)d_in[6];
    const float* b1  = (const float*)d_in[7];
    const float* W2  = (const float*)d_in[8];
    const float* a2s = (const float*)d_in[9];
    const float* a2d = (const float*)d_in[10];
    const float* b2  = (const float*)d_in[11];
    const float* fcw = (const float*)d_in[12];
    const float* fcb = (const float*)d_in[13];

    float* out_main = (float*)d_out;                        // [20000,128]
    float* out_pool = (float*)d_out + (size_t)N_NODES * C2; // [100,128]

    char* p = (char*)d_ws;
    auto alloc = [&](size_t bytes) {
        char* r = p;
        p += (bytes + 255) & ~(size_t)255;
        return r;
    };
    unsigned short* gn   = (unsigned short*)alloc(sizeof(short) * (size_t)N_NODES * C1);
    unsigned short* W2p  = (unsigned short*)alloc(sizeof(short) * C1 * C2);
    unsigned short* W1p  = (unsigned short*)alloc(sizeof(short) * HEADS * F_IN * F_IN);
    f16*   FCp     = (f16*)alloc(sizeof(f16) * C2 * C2);
    f16*   feats16 = (f16*)alloc(sizeof(f16) * (size_t)N_NODES * F_IN);
    f16*   xw2h    = (f16*)alloc(sizeof(f16) * (size_t)N_NODES * C2);
    f16*   x2h     = (f16*)alloc(sizeof(f16) * (size_t)N_NODES * C2);
    float* WAs    = (float*)alloc(sizeof(float) * C1);
    float* WAd    = (float*)alloc(sizeof(float) * C1);
    float* s1s    = (float*)alloc(sizeof(float) * N_NODES * HEADS);
    float* s1d    = (float*)alloc(sizeof(float) * N_NODES * HEADS);
    float* s2s    = (float*)alloc(sizeof(float) * N_NODES);
    float* s2d    = (float*)alloc(sizeof(float) * N_NODES);
    int* cursor   = (int*)alloc(sizeof(int) * N_NODES);       // per-dst fill count
    int* csr_src  = (int*)alloc(sizeof(int) * N_NODES * CAP); // bucket CSR

    prep_kernel<<<CURZ_BLOCKS + W2P_BLOCKS + W1P_BLOCKS + FCP_BLOCKS + F16_BLOCKS + 1, 256, 0, stream>>>(
        cursor, W2, W2p, W1, W1p, fcw, FCp, a1s, a1d, WAs, WAd, feats, feats16);
    scatter_score_kernel<<<SCAT_BLOCKS + (N_NODES + 63) / 64, 256, 0, stream>>>(
        ei, cursor, csr_src, feats, WAs, WAd, s1s, s1d);

    aggg1_kernel<<<2500, 256, 0, stream>>>(feats16, s1s, s1d, cursor, csr_src, gn);
    h1gemm2_kernel<<<625, 256, 0, stream>>>(gn, W1p, b1, W2p, a2s, a2d, xw2h, s2s, s2d);
    agg2_kernel<<<2500, 256, 0, stream>>>(xw2h, s2s, s2d, cursor, csr_src, b2, x2h);
    fc_pool_kernel<<<FCB + NB / 2, 256, 0, stream>>>(x2h, FCp, fcw, fcb, out_main, out_pool);
}

// Round 12
// 167.287 us; speedup vs baseline: 2.1648x; 1.1975x over previous
//
#include <hip/hip_runtime.h>

// Problem constants (fixed by the reference)
#define N_NODES 20000
#define N_EDGES 320000
#define ETOT    (N_EDGES + N_NODES)   // edges + self-loops = 340000
#define HEADS   10
#define F_IN    32
#define C1      (HEADS * F_IN)        // 320
#define C2      128
#define NB      100
#define PER     200
#define CAP     96                    // CSR bucket capacity (max in-degree << 96)
#define HSTRIDE 328                   // padded h1-tile row stride (ushort)
#define X2STRIDE 136                  // padded x2-tile row stride (f16) -> 2-way-free banks

typedef __attribute__((ext_vector_type(8))) short bf16x8;   // MFMA A/B frag (4 VGPRs)
typedef __attribute__((ext_vector_type(4))) float floatx4;  // MFMA C/D frag
typedef _Float16 f16;
typedef _Float16 f16x2 __attribute__((ext_vector_type(2)));
typedef _Float16 f16x8 __attribute__((ext_vector_type(8)));

static __device__ __forceinline__ unsigned short f2bf(float f) {
    unsigned int u = __float_as_uint(f);
    unsigned int r = (u + 0x7fffu + ((u >> 16) & 1u)) >> 16;   // RNE
    return (unsigned short)r;
}

// ---------------------------------------------------------------------------
// Combined prep: cursor+pooled zero + W2/W1/FC MFMA B-frag prep + WA fold
// + feats->f16
// ---------------------------------------------------------------------------
#define CURZ_BLOCKS ((N_NODES + 255) / 256)             // 79
#define PLZ_BLOCKS  ((NB * C2 + 255) / 256)             // 50
#define W2P_BLOCKS  ((C1 * C2 + 255) / 256)             // 160
#define W1P_BLOCKS  ((HEADS * F_IN * F_IN + 255) / 256) // 40
#define FCP_BLOCKS  ((C2 * C2 + 255) / 256)             // 64
#define F16_BLOCKS  ((N_NODES * F_IN / 4 + 255) / 256)  // 625 (x4 vectorized)
__global__ void prep_kernel(int* __restrict__ cursor, int* __restrict__ pooledi,
                            const float* __restrict__ W2, unsigned short* __restrict__ W2p,
                            const float* __restrict__ W1, unsigned short* __restrict__ W1p,
                            const float* __restrict__ fcw, f16* __restrict__ FCp,
                            const float* __restrict__ a1s, const float* __restrict__ a1d,
                            float* __restrict__ WAs, float* __restrict__ WAd,
                            const float* __restrict__ feats, f16* __restrict__ feats16) {
    unsigned int b = blockIdx.x;
    if (b < CURZ_BLOCKS) {
        int o = b * 256 + threadIdx.x;
        if (o < N_NODES) cursor[o] = 0;
        return;
    }
    b -= CURZ_BLOCKS;
    if (b < PLZ_BLOCKS) {
        int o = b * 256 + threadIdx.x;
        if (o < NB * C2) pooledi[o] = 0;   // 0.0f bits; x2 >= 0 so identity for max
        return;
    }
    b -= PLZ_BLOCKS;
    if (b < W2P_BLOCKS) {
        int o = b * 256 + threadIdx.x;   // 40960
        if (o >= C1 * C2) return;
        int j    = o & 7;
        int lane = (o >> 3) & 63;
        int ct   = (o >> 9) & 7;
        int kb   = o >> 12;
        int k = kb * 32 + (lane >> 4) * 8 + j;
        int n = ct * 16 + (lane & 15);
        W2p[o] = f2bf(W2[k * C2 + n]);
        return;
    }
    b -= W2P_BLOCKS;
    if (b < W1P_BLOCKS) {
        // B-frag for h1 GEMM: W1p[((h*2+ct)*64+lane)*8+j] = W1[quad*8+j][h*32+ct*16+col]
        int o = b * 256 + threadIdx.x;   // 10240
        if (o >= HEADS * F_IN * F_IN) return;
        int j    = o & 7;
        int lane = (o >> 3) & 63;
        int ct   = (o >> 9) & 1;
        int h    = o >> 10;
        int k = (lane >> 4) * 8 + j;
        int f = ct * 16 + (lane & 15);
        W1p[o] = f2bf(W1[k * C1 + h * 32 + f]);
        return;
    }
    b -= W1P_BLOCKS;
    if (b < FCP_BLOCKS) {
        // B-frag (f16) for fc GEMM, K=128: kb<4, ct<8
        int o = b * 256 + threadIdx.x;   // 16384
        if (o >= C2 * C2) return;
        int j    = o & 7;
        int lane = (o >> 3) & 63;
        int ct   = (o >> 9) & 7;
        int kb   = o >> 12;
        int k = kb * 32 + (lane >> 4) * 8 + j;
        int n = ct * 16 + (lane & 15);
        FCp[o] = (f16)fcw[k * C2 + n];
        return;
    }
    b -= FCP_BLOCKS;
    if (b < F16_BLOCKS) {
        int o = b * 256 + threadIdx.x;
        if (o < N_NODES * F_IN / 4) {
            float4 v = ((const float4*)feats)[o];
            f16* d = feats16 + 4 * o;
            d[0] = (f16)v.x; d[1] = (f16)v.y; d[2] = (f16)v.z; d[3] = (f16)v.w;
        }
        return;
    }
    // one block: fold attention vectors through W1 -> WAs/WAd [32][10]
    int t = threadIdx.x;
    for (int o = t; o < C1; o += 256) {
        int k = o & 31, h = o >> 5;
        float ss = 0.f, dd = 0.f;
#pragma unroll
        for (int f = 0; f < F_IN; f++) {
            float wv = W1[k * C1 + h * 32 + f];
            ss += wv * a1s[h * 32 + f];
            dd += wv * a1d[h * 32 + f];
        }
        WAs[k * HEADS + h] = ss;
        WAd[k * HEADS + h] = dd;
    }
}

// ---------------------------------------------------------------------------
// Fused: bucket-CSR scatter + layer-1 scores (independent work)
// ---------------------------------------------------------------------------
#define SCAT_BLOCKS ((ETOT + 255) / 256)
__global__ __launch_bounds__(256) void scatter_score_kernel(
        const int* __restrict__ ei, int* __restrict__ cursor, int* __restrict__ csr_src,
        const float* __restrict__ feats, const float* __restrict__ WAs,
        const float* __restrict__ WAd, float* __restrict__ s_src,
        float* __restrict__ s_dst) {
    if (blockIdx.x < SCAT_BLOCKS) {
        int e = blockIdx.x * 256 + threadIdx.x;
        if (e >= ETOT) return;
        int s, d;
        if (e < N_EDGES) { s = ei[e]; d = ei[N_EDGES + e]; }
        else             { s = e - N_EDGES; d = s; }
        int pos = atomicAdd(&cursor[d], 1);
        csr_src[(size_t)d * CAP + pos] = s;
        return;
    }
    __shared__ __align__(16) float A[64 * F_IN];   // 8 KB
    __shared__ float Ws[C1], Wd[C1];
    int t = threadIdx.x;
    int n0 = (blockIdx.x - SCAT_BLOCKS) * 64;
    int nrows = min(64, N_NODES - n0);
    if (nrows <= 0) return;
    for (int i = t; i < C1; i += 256) { Ws[i] = WAs[i]; Wd[i] = WAd[i]; }
    const float4* fs = (const float4*)(feats + (size_t)n0 * F_IN);
    float4* Af = (float4*)A;
    for (int i = t; i < nrows * 8; i += 256) Af[i] = fs[i];
    __syncthreads();
    for (int o = t; o < nrows * HEADS; o += 256) {
        int nl = o / HEADS, h = o - nl * HEADS;
        const float* ar = A + nl * F_IN;
        float ss = 0.f, dd = 0.f;
#pragma unroll
        for (int k = 0; k < F_IN; k++) {
            float av = ar[k];
            ss += av * Ws[k * HEADS + h];
            dd += av * Wd[k * HEADS + h];
        }
        s_src[(size_t)(n0 + nl) * HEADS + h] = ss;
        s_dst[(size_t)(n0 + nl) * HEADS + h] = dd;
    }
}

// ---------------------------------------------------------------------------
// Layer-1 gather: gn[n,h,k] = (sum_e p_eh * feats[s_e,k]) / l_h   (bf16 out)
// ONE WAVE per node (1 node/wave — 20000 waves), no block barriers.
// Weights staged TRANSPOSED as f16 (P[h][e]); value loop: 4 edges/step via
// half-owned edge pairs, fdot2 accumulates value and l sums in fp32.
// ---------------------------------------------------------------------------
__global__ __launch_bounds__(256) void aggg1_kernel(
        const f16* __restrict__ feats16, const float* __restrict__ s_src,
        const float* __restrict__ s_dst, const int* __restrict__ deg_arr,
        const int* __restrict__ csr_src, unsigned short* __restrict__ gn) {
    __shared__ __align__(4) f16 shP[4][HEADS * 64];   // 1.25 KB / slot
    __shared__ __align__(8) int shS[4][64];
    int wslot = threadIdx.x >> 6;
    int n = blockIdx.x * 4 + wslot;                   // 20000 waves, 1 node each
    int lane = threadIdx.x & 63;
    int k = lane & 31, half = lane >> 5;
    f16* P = shP[wslot];
    int* S = shS[wslot];
    const f16x2 ones = {(f16)1.f, (f16)1.f};

    int beg = n * CAP, deg = deg_arr[n];
    const float* sdp = s_dst + (size_t)n * HEADS;
    float sd[10];
#pragma unroll
    for (int q = 0; q < 5; q++) {
        float2 v = *(const float2*)(sdp + 2 * q);
        sd[2 * q] = v.x; sd[2 * q + 1] = v.y;
    }
    float g[10], la[10];
#pragma unroll
    for (int h = 0; h < 10; h++) { g[h] = 0.f; la[h] = 0.f; }

    for (int c0 = 0; c0 < deg; c0 += 64) {
        int dc = min(deg - c0, 64);
        bool act = lane < dc;
        int s_e = csr_src[beg + c0 + min(lane, dc - 1)];
        const float* ssp = s_src + (size_t)s_e * HEADS;
        float p[10];
#pragma unroll
        for (int q = 0; q < 5; q++) {
            float2 v = *(const float2*)(ssp + 2 * q);
            float e0 = v.x + sd[2 * q];
            float e1 = v.y + sd[2 * q + 1];
            e0 = (e0 >= 0.f) ? e0 : 0.2f * e0;   // leaky_relu(0.2)
            e1 = (e1 >= 0.f) ? e1 : 0.2f * e1;
            p[2 * q]     = act ? __expf(e0) : 0.f;
            p[2 * q + 1] = act ? __expf(e1) : 0.f;
        }
        // stage transposed f16 weights; pad edges carry p = 0
        S[lane] = s_e;
#pragma unroll
        for (int h = 0; h < 10; h++) P[h * 64 + lane] = (f16)p[h];
        asm volatile("s_waitcnt lgkmcnt(0)" ::: "memory");

        int dcp = (dc + 3) & ~3;
        for (int i = 0; i < dcp; i += 4) {
            int e0 = i + half * 2;               // this half's edge pair
            int2 ss2 = *(const int2*)&S[e0];
            f16x2 v;
            v.x = feats16[(size_t)ss2.x * F_IN + k];
            v.y = feats16[(size_t)ss2.y * F_IN + k];
#pragma unroll
            for (int h = 0; h < 10; h++) {
                f16x2 pp = *(const f16x2*)&P[h * 64 + e0];
                g[h]  = __builtin_amdgcn_fdot2(pp, v, g[h], false);
                la[h] = __builtin_amdgcn_fdot2(pp, ones, la[h], false);
            }
        }
        asm volatile("s_waitcnt lgkmcnt(0)" ::: "memory");  // reads done before next chunk
    }
#pragma unroll
    for (int h = 0; h < 10; h++) {
        g[h]  += __shfl_xor(g[h], 32);
        la[h] += __shfl_xor(la[h], 32);
    }
    if (half == 0) {
        unsigned short* gp = gn + (size_t)n * C1 + k;
#pragma unroll
        for (int h = 0; h < 10; h++)
            gp[h * 32] = f2bf(g[h] / fmaxf(la[h], 1e-16f));
    }
}

// ---------------------------------------------------------------------------
// Fused h1 + gemm2: per 16-row tile (2 waves/tile):
//   phase 1: h1 = ELU(gn @ W1 + b1) per head, staged bf16 in padded LDS tile
//   phase 2: xw2 = h1 @ W2 (f16 out) + fused s2 scores
// ---------------------------------------------------------------------------
__global__ __launch_bounds__(256) void h1gemm2_kernel(
        const unsigned short* __restrict__ gn, const unsigned short* __restrict__ W1p,
        const float* __restrict__ b1, const unsigned short* __restrict__ W2p,
        const float* __restrict__ a_src, const float* __restrict__ a_dst,
        f16* __restrict__ xw2h, float* __restrict__ s_src2, float* __restrict__ s_dst2) {
    __shared__ unsigned short H[2][16 * HSTRIDE];   // 21 KB
    __shared__ float redS[2][2][16], redD[2][2][16];
    int waveId = threadIdx.x >> 6;
    int tl = waveId >> 1;                // tile slot in block
    int w  = waveId & 1;                 // wave within tile
    int tile = blockIdx.x * 2 + tl;      // 625 blocks x 2 = 1250 tiles exactly
    int lane = threadIdx.x & 63;
    int quad = lane >> 4, col = lane & 15;
    int row0 = tile * 16;

    // ---- phase 1: h1 for heads 5w..5w+4 ----
#pragma unroll
    for (int hh = 0; hh < 5; hh++) {
        int h = w * 5 + hh;
        bf16x8 a = *(const bf16x8*)(gn + (size_t)(row0 + col) * C1 + h * 32 + quad * 8);
        bf16x8 bA = ((const bf16x8*)W1p)[(h * 2 + 0) * 64 + lane];
        bf16x8 bB = ((const bf16x8*)W1p)[(h * 2 + 1) * 64 + lane];
        floatx4 z = {0.f, 0.f, 0.f, 0.f};
        floatx4 c0 = __builtin_amdgcn_mfma_f32_16x16x32_bf16(a, bA, z, 0, 0, 0);
        floatx4 c1 = __builtin_amdgcn_mfma_f32_16x16x32_bf16(a, bB, z, 0, 0, 0);
        float bias0 = b1[h * 32 + col];
        float bias1 = b1[h * 32 + 16 + col];
#pragma unroll
        for (int reg = 0; reg < 4; reg++) {
            int r = quad * 4 + reg;
            float o0 = c0[reg] + bias0;
            float o1 = c1[reg] + bias1;
            o0 = (o0 > 0.f) ? o0 : (__expf(o0) - 1.f);
            o1 = (o1 > 0.f) ? o1 : (__expf(o1) - 1.f);
            H[tl][r * HSTRIDE + h * 32 + col]      = f2bf(o0);
            H[tl][r * HSTRIDE + h * 32 + 16 + col] = f2bf(o1);
        }
    }
    __syncthreads();

    // ---- phase 2: gemm2, wave w covers cols 64w..64w+63 (ct = 4w..4w+3) ----
    floatx4 acc[4];
#pragma unroll
    for (int c = 0; c < 4; c++) acc[c] = (floatx4){0.f, 0.f, 0.f, 0.f};
    const bf16x8* pb = (const bf16x8*)W2p;
#pragma unroll
    for (int kb = 0; kb < 10; kb++) {
        bf16x8 a = *(const bf16x8*)&H[tl][(lane & 15) * HSTRIDE + kb * 32 + quad * 8];
#pragma unroll
        for (int c = 0; c < 4; c++) {
            bf16x8 b = pb[(kb * 8 + (4 * w + c)) * 64 + lane];
            acc[c] = __builtin_amdgcn_mfma_f32_16x16x32_bf16(a, b, acc[c], 0, 0, 0);
        }
    }
    float asv[4], adv[4];
#pragma unroll
    for (int c = 0; c < 4; c++) {
        asv[c] = a_src[(4 * w + c) * 16 + col];
        adv[c] = a_dst[(4 * w + c) * 16 + col];
    }
#pragma unroll
    for (int reg = 0; reg < 4; reg++) {
        int row = row0 + quad * 4 + reg;
        float vs = 0.f, vd = 0.f;
#pragma unroll
        for (int c = 0; c < 4; c++) {
            float v = acc[c][reg];
            xw2h[(size_t)row * C2 + (4 * w + c) * 16 + col] = (f16)v;
            vs += v * asv[c];
            vd += v * adv[c];
        }
#pragma unroll
        for (int off = 8; off >= 1; off >>= 1) {
            vs += __shfl_xor(vs, off);
            vd += __shfl_xor(vd, off);
        }
        if (col == 0) { redS[tl][w][quad * 4 + reg] = vs; redD[tl][w][quad * 4 + reg] = vd; }
    }
    __syncthreads();
    if (w == 0) {
        if (lane < 16)
            s_src2[row0 + lane] = redS[tl][0][lane] + redS[tl][1][lane];
        else if (lane < 32)
            s_dst2[row0 + lane - 16] = redD[tl][0][lane - 16] + redD[tl][1][lane - 16];
    }
}

// ---------------------------------------------------------------------------
// Fused layer-2 aggregation + fc: block = one 16-node tile.
//   phase 1: wave w computes x2 (ReLU'd, f16) for nodes 16b+4w..+3 into LDS
//            + tile-local per-channel max -> atomicMax into pooled (f32 bits)
//   phase 2: out = relu(X @ fc_w + fc_b) via f16 MFMA from the LDS tile
// ---------------------------------------------------------------------------
__global__ __launch_bounds__(256) void agg2fc_kernel(
        const f16* __restrict__ xw2h, const float* __restrict__ s_src2,
        const float* __restrict__ s_dst2, const int* __restrict__ deg_arr,
        const int* __restrict__ csr_src, const float* __restrict__ b2,
        const f16* __restrict__ FCp, const float* __restrict__ fcb,
        float* __restrict__ out, int* __restrict__ pooledi) {
    __shared__ __align__(8) int2 shE[4][64];          // 2 KB
    __shared__ __align__(16) f16 X[16 * X2STRIDE];    // 4.25 KB
    int wslot = threadIdx.x >> 6;
    int lane = threadIdx.x & 63;
    int tile = blockIdx.x;               // 1250
    int row0 = tile * 16;
    int2* E = shE[wslot];

    // ---- phase 1: 4 nodes per wave ----
#pragma unroll
    for (int rep = 0; rep < 4; rep++) {
        int r = wslot * 4 + rep;
        int n = row0 + r;
        int beg = n * CAP, deg = deg_arr[n];
        float sd = s_dst2[n];
        float l = 0.f, a0 = 0.f, a1 = 0.f;

        for (int c0 = 0; c0 < deg; c0 += 64) {
            int dc = min(deg - c0, 64);
            bool act = lane < dc;
            int s_e = csr_src[beg + c0 + min(lane, dc - 1)];
            float e = s_src2[s_e] + sd;
            e = (e >= 0.f) ? e : 0.2f * e;
            float p = act ? __expf(e) : 0.f;
            float su = p;
#pragma unroll
            for (int off = 32; off >= 1; off >>= 1) su += __shfl_xor(su, off);
            l += su;

            E[lane] = make_int2(s_e, __float_as_int(p));
            asm volatile("s_waitcnt lgkmcnt(0)" ::: "memory");

            int dcr = (dc + 3) & ~3;                  // pad rows have p=0
            for (int i = 0; i < dcr; i += 4) {
                int2 e0 = E[i + 0], e1 = E[i + 1], e2 = E[i + 2], e3 = E[i + 3];
                f16x2 v0 = *(const f16x2*)(xw2h + (size_t)e0.x * C2 + 2 * lane);
                f16x2 v1 = *(const f16x2*)(xw2h + (size_t)e1.x * C2 + 2 * lane);
                f16x2 v2 = *(const f16x2*)(xw2h + (size_t)e2.x * C2 + 2 * lane);
                f16x2 v3 = *(const f16x2*)(xw2h + (size_t)e3.x * C2 + 2 * lane);
                float p0 = __int_as_float(e0.y), p1 = __int_as_float(e1.y);
                float p2 = __int_as_float(e2.y), p3 = __int_as_float(e3.y);
                a0 += p0 * (float)v0.x + p1 * (float)v1.x + p2 * (float)v2.x + p3 * (float)v3.x;
                a1 += p0 * (float)v0.y + p1 * (float)v1.y + p2 * (float)v2.y + p3 * (float)v3.y;
            }
            asm volatile("s_waitcnt lgkmcnt(0)" ::: "memory");
        }

        float linv = 1.f / fmaxf(l, 1e-16f);
        float2 bb = *(const float2*)(b2 + 2 * lane);
        f16x2 o;
        o.x = (f16)fmaxf(a0 * linv + bb.x, 0.f);
        o.y = (f16)fmaxf(a1 * linv + bb.y, 0.f);
        *(f16x2*)&X[r * X2STRIDE + 2 * lane] = o;
    }
    __syncthreads();

    // ---- phase 2a: fc MFMA — wave w covers ct = 2w, 2w+1 ----
    int quad = lane >> 4, col = lane & 15;
    floatx4 acc[2];
    acc[0] = (floatx4){0.f, 0.f, 0.f, 0.f};
    acc[1] = (floatx4){0.f, 0.f, 0.f, 0.f};
    const f16x8* pb = (const f16x8*)FCp;
#pragma unroll
    for (int kb = 0; kb < 4; kb++) {
        f16x8 a = *(const f16x8*)&X[(lane & 15) * X2STRIDE + kb * 32 + quad * 8];
#pragma unroll
        for (int c = 0; c < 2; c++) {
            int ct = wslot * 2 + c;
            f16x8 b = pb[(kb * 8 + ct) * 64 + lane];
            acc[c] = __builtin_amdgcn_mfma_f32_16x16x32_f16(a, b, acc[c], 0, 0, 0);
        }
    }
#pragma unroll
    for (int c = 0; c < 2; c++) {
        int ct = wslot * 2 + c;
        float bias = fcb[ct * 16 + col];
#pragma unroll
        for (int reg = 0; reg < 4; reg++) {
            int row = row0 + quad * 4 + reg;
            out[(size_t)row * C2 + ct * 16 + col] = fmaxf(acc[c][reg] + bias, 0.f);
        }
    }

    // ---- phase 2b: tile-local pooling max + atomicMax (threads 0..127) ----
    if (threadIdx.x < C2) {
        int c = threadIdx.x;
        int gA = row0 / PER;
        int gB = (row0 + 15) / PER;
        float mA = 0.f, mB = 0.f;        // x2 >= 0, 0 is identity
#pragma unroll
        for (int r = 0; r < 16; r++) {
            float v = (float)X[r * X2STRIDE + c];
            if ((row0 + r) / PER == gA) mA = fmaxf(mA, v);
            else                        mB = fmaxf(mB, v);
        }
        atomicMax(&pooledi[gA * C2 + c], __float_as_int(mA));
        if (gB != gA) atomicMax(&pooledi[gB * C2 + c], __float_as_int(mB));
    }
}

// ---------------------------------------------------------------------------
// Final pooled fc: relu(pooled @ fc_w + fc_b)
// ---------------------------------------------------------------------------
__global__ void poolfc_kernel(const int* __restrict__ pooledi, const float* __restrict__ fcw,
                              const float* __restrict__ fcb, float* __restrict__ outp) {
    __shared__ float mx[C2];
    int g = blockIdx.x, t = threadIdx.x;   // 128
    mx[t] = __int_as_float(pooledi[g * C2 + t]);
    __syncthreads();
    float acc = 0.f;
    for (int k = 0; k < C2; k++) acc += mx[k] * fcw[k * C2 + t];
    outp[g * C2 + t] = fmaxf(acc + fcb[t], 0.f);
}

// ---------------------------------------------------------------------------
extern "C" void kernel_launch(void* const* d_in, const int* in_sizes, int n_in,
                              void* d_out, int out_size, void* d_ws, size_t ws_size,
                              hipStream_t stream) {
    const float* feats = (const float*)d_in[0];
    const int*   ei    = (const int*)d_in[1];
    const float* W1  = (const float*)d_in[4];
    const float* a1s = (const float*)d_in[5];
    const float* a1d = (const float*)d_in[6];
    const float* b1  = (const float*)d_in[7];
    const float* W2  = (const float*)d_in[8];
    const float* a2s = (const float*)d_in[9];
    const float* a2d = (const float*)d_in[10];
    const float* b2  = (const float*)d_in[11];
    const float* fcw = (const float*)d_in[12];
    const float* fcb = (const float*)d_in[13];

    float* out_main = (float*)d_out;                        // [20000,128]
    float* out_pool = (float*)d_out + (size_t)N_NODES * C2; // [100,128]

    char* p = (char*)d_ws;
    auto alloc = [&](size_t bytes) {
        char* r = p;
        p += (bytes + 255) & ~(size_t)255;
        return r;
    };
    unsigned short* gn   = (unsigned short*)alloc(sizeof(short) * (size_t)N_NODES * C1);
    unsigned short* W2p  = (unsigned short*)alloc(sizeof(short) * C1 * C2);
    unsigned short* W1p  = (unsigned short*)alloc(sizeof(short) * HEADS * F_IN * F_IN);
    f16*   FCp     = (f16*)alloc(sizeof(f16) * C2 * C2);
    f16*   feats16 = (f16*)alloc(sizeof(f16) * (size_t)N_NODES * F_IN);
    f16*   xw2h    = (f16*)alloc(sizeof(f16) * (size_t)N_NODES * C2);
    float* WAs    = (float*)alloc(sizeof(float) * C1);
    float* WAd    = (float*)alloc(sizeof(float) * C1);
    float* s1s    = (float*)alloc(sizeof(float) * N_NODES * HEADS);
    float* s1d    = (float*)alloc(sizeof(float) * N_NODES * HEADS);
    float* s2s    = (float*)alloc(sizeof(float) * N_NODES);
    float* s2d    = (float*)alloc(sizeof(float) * N_NODES);
    int* cursor   = (int*)alloc(sizeof(int) * N_NODES);       // per-dst fill count
    int* pooledi  = (int*)alloc(sizeof(int) * NB * C2);       // pooled max (f32 bits)
    int* csr_src  = (int*)alloc(sizeof(int) * N_NODES * CAP); // bucket CSR

    prep_kernel<<<CURZ_BLOCKS + PLZ_BLOCKS + W2P_BLOCKS + W1P_BLOCKS + FCP_BLOCKS + F16_BLOCKS + 1,
                  256, 0, stream>>>(
        cursor, pooledi, W2, W2p, W1, W1p, fcw, FCp, a1s, a1d, WAs, WAd, feats, feats16);
    scatter_score_kernel<<<SCAT_BLOCKS + (N_NODES + 63) / 64, 256, 0, stream>>>(
        ei, cursor, csr_src, feats, WAs, WAd, s1s, s1d);

    aggg1_kernel<<<5000, 256, 0, stream>>>(feats16, s1s, s1d, cursor, csr_src, gn);
    h1gemm2_kernel<<<625, 256, 0, stream>>>(gn, W1p, b1, W2p, a2s, a2d, xw2h, s2s, s2d);
    agg2fc_kernel<<<1250, 256, 0, stream>>>(xw2h, s2s, s2d, cursor, csr_src, b2,
                                            FCp, fcb, out_main, pooledi);
    poolfc_kernel<<<NB, C2, 0, stream>>>(pooledi, fcw, fcb, out_pool);
}